// Round 1
// baseline (265.046 us; speedup 1.0000x reference)
//
#include <hip/hip_runtime.h>
#include <math.h>

#define BB 4
#define NLL 2048
#define CC 128
#define HH 128
#define WW 128
#define NPTS0 32
#define NPTS1 8
#define PP 64
#define FDIM 5
#define FCK (CC*NPTS1 + FDIM)   // 1029

// ---------------------------------------------------------------------------
// Kernel 1: transpose feature map (B,C,H,W) -> (B,H,W,C) so the per-point
// channel gather becomes contiguous 512B runs.
// ---------------------------------------------------------------------------
__global__ __launch_bounds__(256)
void transpose_fm(const float* __restrict__ fm, float* __restrict__ fmT) {
    __shared__ float tile[32][33];
    int x0 = blockIdx.x * 32;          // W tile
    int c0 = blockIdx.y * 32;          // C tile
    int by = blockIdx.z;               // b*H + y
    int b = by / HH, y = by % HH;
    int tx = threadIdx.x;              // 0..31
    int ty = threadIdx.y;              // 0..7

    const float* src = fm + (size_t)b * CC * HH * WW + (size_t)y * WW;
    #pragma unroll
    for (int i = 0; i < 4; ++i) {
        int c = c0 + ty + 8 * i;
        tile[ty + 8 * i][tx] = src[(size_t)c * HH * WW + x0 + tx];
    }
    __syncthreads();
    float* dst = fmT + (size_t)(b * HH + y) * WW * CC;
    #pragma unroll
    for (int i = 0; i < 4; ++i) {
        int x = x0 + ty + 8 * i;
        dst[(size_t)x * CC + c0 + tx] = tile[tx][ty + 8 * i];
    }
}

// ---------------------------------------------------------------------------
// Kernel 2: fully fused per-line pipeline. One block (256 thr) per line.
//   gather+bilinear+maxpool -> bn1/relu -> conv1(1x1) -> bn2/relu ->
//   conv2(3) -> bn3/relu -> conv3(1x1) -> residual -> relu -> fc2 -> softmax
// ---------------------------------------------------------------------------
template<bool TRANS>
__global__ __launch_bounds__(256)
void line_kernel(const float* __restrict__ fm,   // TRANS ? (B,H,W,C) : (B,C,H,W)
                 const float* __restrict__ lines,
                 const float* __restrict__ bn1_g, const float* __restrict__ bn1_b,
                 const float* __restrict__ w1,    const float* __restrict__ b1,
                 const float* __restrict__ bn2_g, const float* __restrict__ bn2_b,
                 const float* __restrict__ w2,    const float* __restrict__ b2,
                 const float* __restrict__ bn3_g, const float* __restrict__ bn3_b,
                 const float* __restrict__ w3,    const float* __restrict__ b3,
                 const float* __restrict__ fcw,   const float* __restrict__ fcb,
                 float* __restrict__ out) {
    __shared__ int   s_ix0[32], s_ix1[32], s_iy0[32], s_iy1[32];
    __shared__ float s_wA[32], s_wB[32], s_wC[32], s_wD[32];
    __shared__ float xs [8][132];   // raw maxpooled x, [k][c]   (residual source)
    __shared__ float ybn[8][132];   // relu(bn1(x)), [k][c]
    __shared__ float z1 [64][12];   // relu(bn2(conv1)), [p][0..9], halo 0/9 = 0
    __shared__ float z2 [64][8];    // relu(bn3(conv2)), [p][k]
    __shared__ float s_feat[8];
    __shared__ float s_red[16];

    const int L   = blockIdx.x;       // line id, 0..B*NL-1
    const int b   = L / NLL;
    const int tid = threadIdx.x;
    const float inv_s = 1.0f / sqrtf(1.0f + 1e-5f);

    const float* ln = lines + (size_t)L * 4;   // ux, uy, vx, vy

    // ---- phase 0: per-point sample coords/weights + line features ----
    if (tid < 32) {
        float lam = (float)tid * (1.0f / 31.0f);
        float om  = 1.0f - lam;
        float px = ln[0] * lam + ln[2] * om - 0.5f;
        float py = ln[1] * lam + ln[3] * om - 0.5f;
        float px0 = fminf(fmaxf(floorf(px), 0.0f), 127.0f);
        float py0 = fminf(fmaxf(floorf(py), 0.0f), 127.0f);
        float px1 = fminf(px0 + 1.0f, 127.0f);
        float py1 = fminf(py0 + 1.0f, 127.0f);
        s_ix0[tid] = (int)px0; s_ix1[tid] = (int)px1;
        s_iy0[tid] = (int)py0; s_iy1[tid] = (int)py1;
        float ax = px1 - px, bxv = px - px0, ay = py1 - py, byv = py - py0;
        // EXACT reference pairing (its bilinear is x/y-weight swapped):
        s_wA[tid] = ax  * ay;    // corner (py0, px0)
        s_wB[tid] = bxv * ay;    // corner (py1, px0)
        s_wC[tid] = ax  * byv;   // corner (py0, px1)
        s_wD[tid] = bxv * byv;   // corner (py1, px1)
    }
    if (tid == 0) {
        float ux = ln[0], uy = ln[1], vx = ln[2], vy = ln[3];
        float dx = ux - vx, dy = uy - vy;
        float d = sqrtf(dx * dx + dy * dy);
        d = fmaxf(d, 1e-6f);
        s_feat[0] = ux * (1.0f / 128.0f);
        s_feat[1] = uy * (1.0f / 128.0f);
        s_feat[2] = vx * (1.0f / 128.0f);
        s_feat[3] = vy * (1.0f / 128.0f);
        s_feat[4] = d;
    }
    __syncthreads();

    // ---- phase 1: gather + bilinear + maxpool(4) -> xs[k][c] ----
    {
        int cq = tid & 31;        // channel quad id
        int k  = tid >> 5;        // output position 0..7
        int c0 = cq * 4;
        float4 acc;
        acc.x = -INFINITY; acc.y = -INFINITY; acc.z = -INFINITY; acc.w = -INFINITY;
        #pragma unroll
        for (int j = 0; j < 4; ++j) {
            int pt = k * 4 + j;
            int ix0 = s_ix0[pt], ix1 = s_ix1[pt];
            int iy0 = s_iy0[pt], iy1 = s_iy1[pt];
            float wA = s_wA[pt], wB = s_wB[pt], wC = s_wC[pt], wD = s_wD[pt];
            float4 vA, vB, vC, vD;
            if (TRANS) {
                const float* base = fm + (size_t)b * HH * WW * CC;
                vA = *(const float4*)(base + ((size_t)(iy0 * WW + ix0)) * CC + c0);
                vB = *(const float4*)(base + ((size_t)(iy1 * WW + ix0)) * CC + c0);
                vC = *(const float4*)(base + ((size_t)(iy0 * WW + ix1)) * CC + c0);
                vD = *(const float4*)(base + ((size_t)(iy1 * WW + ix1)) * CC + c0);
            } else {
                const float* base = fm + ((size_t)b * CC + c0) * HH * WW;
                int oA = iy0 * WW + ix0, oB = iy1 * WW + ix0;
                int oC = iy0 * WW + ix1, oD = iy1 * WW + ix1;
                vA.x = base[oA];              vB.x = base[oB];
                vC.x = base[oC];              vD.x = base[oD];
                vA.y = base[HH*WW + oA];      vB.y = base[HH*WW + oB];
                vC.y = base[HH*WW + oC];      vD.y = base[HH*WW + oD];
                vA.z = base[2*HH*WW + oA];    vB.z = base[2*HH*WW + oB];
                vC.z = base[2*HH*WW + oC];    vD.z = base[2*HH*WW + oD];
                vA.w = base[3*HH*WW + oA];    vB.w = base[3*HH*WW + oB];
                vC.w = base[3*HH*WW + oC];    vD.w = base[3*HH*WW + oD];
            }
            float4 v;
            v.x = wA * vA.x + wB * vB.x + wC * vC.x + wD * vD.x;
            v.y = wA * vA.y + wB * vB.y + wC * vC.y + wD * vD.y;
            v.z = wA * vA.z + wB * vB.z + wC * vC.z + wD * vD.z;
            v.w = wA * vA.w + wB * vB.w + wC * vC.w + wD * vD.w;
            acc.x = fmaxf(acc.x, v.x); acc.y = fmaxf(acc.y, v.y);
            acc.z = fmaxf(acc.z, v.z); acc.w = fmaxf(acc.w, v.w);
        }
        *(float4*)(&xs[k][c0]) = acc;   // row stride 132 floats = 33*16B, aligned
    }
    __syncthreads();

    // ---- phase 2: bn1 + relu -> ybn[k][c] ----
    for (int e = tid; e < 1024; e += 256) {
        int k = e >> 7, c = e & 127;
        float s = bn1_g[c] * inv_s;
        ybn[k][c] = fmaxf(xs[k][c] * s + bn1_b[c], 0.0f);
    }
    __syncthreads();

    // ---- phase 3: conv1 (1x1, C->P) + bn2 + relu -> z1[p][1..8] ----
    if (tid < 64) { z1[tid][0] = 0.0f; z1[tid][9] = 0.0f; }
    {
        int p  = tid >> 2;     // 0..63
        int kq = tid & 3;      // 0..3 ; this thread does k = kq and kq+4
        const float* wrow = w1 + p * 128;
        float a0a = 0.f, a0b = 0.f, a1a = 0.f, a1b = 0.f;
        #pragma unroll 8
        for (int c = 0; c < 128; c += 4) {
            float4 w  = *(const float4*)(wrow + c);
            float4 ya = *(const float4*)(&ybn[kq][c]);
            float4 yb = *(const float4*)(&ybn[kq + 4][c]);
            a0a = fmaf(w.x, ya.x, a0a); a0b = fmaf(w.y, ya.y, a0b);
            a0a = fmaf(w.z, ya.z, a0a); a0b = fmaf(w.w, ya.w, a0b);
            a1a = fmaf(w.x, yb.x, a1a); a1b = fmaf(w.y, yb.y, a1b);
            a1a = fmaf(w.z, yb.z, a1a); a1b = fmaf(w.w, yb.w, a1b);
        }
        float s2 = bn2_g[p] * inv_s, bb = bn2_b[p], cb = b1[p];
        z1[p][1 + kq]     = fmaxf((a0a + a0b + cb) * s2 + bb, 0.0f);
        z1[p][1 + kq + 4] = fmaxf((a1a + a1b + cb) * s2 + bb, 0.0f);
    }
    __syncthreads();

    // ---- phase 4: conv2 (3-tap, P->P, pad 1) + bn3 + relu -> z2[p][k] ----
    {
        int p  = tid >> 2;
        int kq = tid & 3;
        const float* wrow = w2 + p * 192;
        float acc0 = 0.f, acc1 = 0.f;
        #pragma unroll 4
        for (int q = 0; q < 64; ++q) {
            float w0 = wrow[q * 3 + 0];
            float w1v = wrow[q * 3 + 1];
            float w2v = wrow[q * 3 + 2];
            const float* zr = &z1[q][0];
            acc0 = fmaf(w0, zr[kq],     acc0);
            acc0 = fmaf(w1v, zr[kq + 1], acc0);
            acc0 = fmaf(w2v, zr[kq + 2], acc0);
            acc1 = fmaf(w0, zr[kq + 4], acc1);
            acc1 = fmaf(w1v, zr[kq + 5], acc1);
            acc1 = fmaf(w2v, zr[kq + 6], acc1);
        }
        float s3 = bn3_g[p] * inv_s, bb = bn3_b[p], cb = b2[p];
        z2[p][kq]     = fmaxf((acc0 + cb) * s3 + bb, 0.0f);
        z2[p][kq + 4] = fmaxf((acc1 + cb) * s3 + bb, 0.0f);
    }
    __syncthreads();

    // ---- phase 5: conv3 (1x1, P->C) + residual + relu + fc2 partials ----
    float part0 = 0.f, part1 = 0.f, part2 = 0.f, part3 = 0.f;
    {
        int c  = tid >> 1;     // 0..127
        int kq = tid & 1;      // k = kq, kq+2, kq+4, kq+6
        const float* wrow = w3 + c * 64;
        float acc[4] = {0.f, 0.f, 0.f, 0.f};
        #pragma unroll 8
        for (int q = 0; q < 64; ++q) {
            float w = wrow[q];
            acc[0] = fmaf(w, z2[q][kq],     acc[0]);
            acc[1] = fmaf(w, z2[q][kq + 2], acc[1]);
            acc[2] = fmaf(w, z2[q][kq + 4], acc[2]);
            acc[3] = fmaf(w, z2[q][kq + 6], acc[3]);
        }
        float cb = b3[c];
        #pragma unroll
        for (int i = 0; i < 4; ++i) {
            int k = kq + 2 * i;
            float v = fmaxf(xs[k][c] + acc[i] + cb, 0.0f);
            int idx = c * 8 + k;
            part0 = fmaf(v, fcw[0 * FCK + idx], part0);
            part1 = fmaf(v, fcw[1 * FCK + idx], part1);
            part2 = fmaf(v, fcw[2 * FCK + idx], part2);
            part3 = fmaf(v, fcw[3 * FCK + idx], part3);
        }
    }
    // wave reduction (64 lanes)
    #pragma unroll
    for (int off = 32; off > 0; off >>= 1) {
        part0 += __shfl_down(part0, off);
        part1 += __shfl_down(part1, off);
        part2 += __shfl_down(part2, off);
        part3 += __shfl_down(part3, off);
    }
    if ((tid & 63) == 0) {
        int w = tid >> 6;
        s_red[w * 4 + 0] = part0; s_red[w * 4 + 1] = part1;
        s_red[w * 4 + 2] = part2; s_red[w * 4 + 3] = part3;
    }
    __syncthreads();
    if (tid == 0) {
        float lg[4];
        #pragma unroll
        for (int o = 0; o < 4; ++o) {
            lg[o] = fcb[o] + s_red[o] + s_red[4 + o] + s_red[8 + o] + s_red[12 + o];
        }
        #pragma unroll
        for (int j = 0; j < FDIM; ++j) {
            float fv = fmaxf(s_feat[j], 0.0f);
            #pragma unroll
            for (int o = 0; o < 4; ++o)
                lg[o] = fmaf(fv, fcw[o * FCK + 1024 + j], lg[o]);
        }
        float m = fmaxf(fmaxf(lg[0], lg[1]), fmaxf(lg[2], lg[3]));
        float e0 = expf(lg[0] - m), e1 = expf(lg[1] - m);
        float e2 = expf(lg[2] - m), e3 = expf(lg[3] - m);
        float inv = 1.0f / (e0 + e1 + e2 + e3);
        float* lo = out + (size_t)L * 4;
        lo[0] = lg[0]; lo[1] = lg[1]; lo[2] = lg[2]; lo[3] = lg[3];
        float* pr = out + (size_t)BB * NLL * 4 + (size_t)L * 4;
        pr[0] = e0 * inv; pr[1] = e1 * inv; pr[2] = e2 * inv; pr[3] = e3 * inv;
    }
}

extern "C" void kernel_launch(void* const* d_in, const int* in_sizes, int n_in,
                              void* d_out, int out_size, void* d_ws, size_t ws_size,
                              hipStream_t stream) {
    const float* fm     = (const float*)d_in[0];
    const float* lines  = (const float*)d_in[1];
    const float* bn1_g  = (const float*)d_in[2];
    const float* bn1_b  = (const float*)d_in[3];
    const float* w1     = (const float*)d_in[4];
    const float* b1     = (const float*)d_in[5];
    const float* bn2_g  = (const float*)d_in[6];
    const float* bn2_b  = (const float*)d_in[7];
    const float* w2     = (const float*)d_in[8];
    const float* b2     = (const float*)d_in[9];
    const float* bn3_g  = (const float*)d_in[10];
    const float* bn3_b  = (const float*)d_in[11];
    const float* w3     = (const float*)d_in[12];
    const float* b3     = (const float*)d_in[13];
    const float* fcw    = (const float*)d_in[14];
    const float* fcb    = (const float*)d_in[15];
    float* out = (float*)d_out;

    const size_t fmT_bytes = (size_t)BB * HH * WW * CC * sizeof(float);
    if (ws_size >= fmT_bytes) {
        float* fmT = (float*)d_ws;
        dim3 tb(32, 8), tg(WW / 32, CC / 32, BB * HH);
        transpose_fm<<<tg, tb, 0, stream>>>(fm, fmT);
        line_kernel<true><<<BB * NLL, 256, 0, stream>>>(
            fmT, lines, bn1_g, bn1_b, w1, b1, bn2_g, bn2_b, w2, b2,
            bn3_g, bn3_b, w3, b3, fcw, fcb, out);
    } else {
        line_kernel<false><<<BB * NLL, 256, 0, stream>>>(
            fm, lines, bn1_g, bn1_b, w1, b1, bn2_g, bn2_b, w2, b2,
            bn3_g, bn3_b, w3, b3, fcw, fcb, out);
    }
}

// Round 2
// 167.394 us; speedup vs baseline: 1.5834x; 1.5834x over previous
//
#include <hip/hip_runtime.h>
#include <math.h>

#define BB 4
#define NLL 2048
#define CC 128
#define HH 128
#define WW 128
#define NPTS0 32
#define NPTS1 8
#define PP 64
#define FDIM 5
#define FCK (CC*NPTS1 + FDIM)   // 1029

typedef __attribute__((ext_vector_type(8))) short bf16x8;
typedef __attribute__((ext_vector_type(4))) float f32x4;

__device__ __forceinline__ unsigned short f2bf(float f) {
    union { float f; unsigned u; } v; v.f = f;
    unsigned u = v.u;
    return (unsigned short)((u + 0x7fffu + ((u >> 16) & 1u)) >> 16);
}

// ---------------------------------------------------------------------------
// Transpose (B,C,H,W) -> (B,H,W,C). v2: 512B-contiguous reads per channel row.
// Block: (b,y) x 32-channel tile, full x=128. 256 threads.
// ---------------------------------------------------------------------------
__global__ __launch_bounds__(256)
void transpose_fm2(const float* __restrict__ fm, float* __restrict__ fmT) {
    __shared__ float tile[32 * 132];
    const int c0 = blockIdx.x * 32;
    const int by = blockIdx.y;            // b*H + y
    const int b = by >> 7, y = by & 127;
    const int t = threadIdx.x;
    const float* src = fm + ((size_t)b * CC) * (HH * WW) + (size_t)y * WW;
    const int x4 = (t & 31) * 4;
    #pragma unroll
    for (int i = 0; i < 4; ++i) {
        int r = (t >> 5) + 8 * i;         // channel row within tile
        *(float4*)&tile[r * 132 + x4] =
            *(const float4*)&src[(size_t)(c0 + r) * (HH * WW) + x4];
    }
    __syncthreads();
    float* dst = fmT + (size_t)by * WW * CC + c0 + (t & 31);
    const int cr = (t & 31) * 132;
    #pragma unroll
    for (int i = 0; i < 16; ++i) {
        int x = (t >> 5) + 8 * i;
        dst[(size_t)x * CC] = tile[cr + x];   // 32 lanes -> 128B contiguous
    }
}

// ---------------------------------------------------------------------------
// Weight prep: fp32 -> bf16, B-operand-friendly [n][k] row-major layouts.
//   W1b[p][c]      (64x128)  = w1[p][c]
//   W2b[t][p][q]   (3x64x64) = w2[p][q][t]
//   W3b[c][q]      (128x64)  = w3[c][q]
// ---------------------------------------------------------------------------
__global__ __launch_bounds__(256)
void prep_weights(const float* __restrict__ w1, const float* __restrict__ w2,
                  const float* __restrict__ w3, unsigned short* __restrict__ W1b,
                  unsigned short* __restrict__ W2b, unsigned short* __restrict__ W3b) {
    int gid = blockIdx.x * 256 + threadIdx.x;
    if (gid < 8192) {
        W1b[gid] = f2bf(w1[gid]);
    } else if (gid < 20480) {
        int g = gid - 8192;
        int tt = g >> 12, r = g & 4095;
        int p = r >> 6, q = r & 63;
        W2b[tt * 4096 + p * 64 + q] = f2bf(w2[p * 192 + q * 3 + tt]);
    } else if (gid < 28672) {
        int g = gid - 20480;
        W3b[g] = f2bf(w3[g]);
    }
}

// ---------------------------------------------------------------------------
// Fused line pipeline, MFMA version. 2 lines per block, 256 threads (4 waves).
// MFMA 16x16x32 bf16 lane mapping (measured m89/m120):
//   A[m=lane&15][k=quad*8+j]   B[k=quad*8+j][n=lane&15]
//   C/D: col=lane&15, row=quad*4+reg
// ---------------------------------------------------------------------------
__global__ __launch_bounds__(256)
void line_mfma(const float* __restrict__ fmT,    // (B,H,W,C)
               const float* __restrict__ lines,
               const float* __restrict__ bn1_g, const float* __restrict__ bn1_b,
               const unsigned short* __restrict__ W1b, const float* __restrict__ b1,
               const float* __restrict__ bn2_g, const float* __restrict__ bn2_b,
               const unsigned short* __restrict__ W2b, const float* __restrict__ b2,
               const float* __restrict__ bn3_g, const float* __restrict__ bn3_b,
               const unsigned short* __restrict__ W3b, const float* __restrict__ b3,
               const float* __restrict__ fcw,   const float* __restrict__ fcb,
               float* __restrict__ out) {
    __shared__ int   s_ix0[64], s_ix1[64], s_iy0[64], s_iy1[64];
    __shared__ float s_wA[64], s_wB[64], s_wC[64], s_wD[64];
    __shared__ float s_xs[16 * 128];             // residual, fp32, [m=line*8+k][c]
    __shared__ unsigned short s_ybn[16 * 136];   // relu(bn1), bf16, [m][c], pad 8
    __shared__ unsigned short s_z1[2 * 10 * 72]; // conv1 out, halo rows 0/9 zero
    __shared__ unsigned short s_z2[16 * 72];     // conv2 out, [m][q]
    __shared__ float s_feat[2][8];
    __shared__ float s_red[4 * 8];               // [wave][line*4+o]

    const int bx  = blockIdx.x;
    const int L0  = bx * 2;
    const int b   = bx >> 10;                    // = L0 / NLL
    const int tid = threadIdx.x;
    const int lane = tid & 63;
    const int wv   = tid >> 6;
    const int quad = lane >> 4;
    const int l16  = lane & 15;
    const float inv_s = 1.0f / sqrtf(1.0f + 1e-5f);

    // ---- P0: per-point coords/weights, line features, halo zeroing ----
    if (tid < 64) {
        int line = tid >> 5, pt = tid & 31;
        const float* ln = lines + (size_t)(L0 + line) * 4;
        float lam = (float)pt * (1.0f / 31.0f);
        float om  = 1.0f - lam;
        float px = ln[0] * lam + ln[2] * om - 0.5f;
        float py = ln[1] * lam + ln[3] * om - 0.5f;
        float px0 = fminf(fmaxf(floorf(px), 0.0f), 127.0f);
        float py0 = fminf(fmaxf(floorf(py), 0.0f), 127.0f);
        float px1 = fminf(px0 + 1.0f, 127.0f);
        float py1 = fminf(py0 + 1.0f, 127.0f);
        s_ix0[tid] = (int)px0; s_ix1[tid] = (int)px1;
        s_iy0[tid] = (int)py0; s_iy1[tid] = (int)py1;
        float ax = px1 - px, bxv = px - px0, ay = py1 - py, byv = py - py0;
        // exact reference pairing (its bilinear weights are x/y-swapped)
        s_wA[tid] = ax  * ay;
        s_wB[tid] = bxv * ay;
        s_wC[tid] = ax  * byv;
        s_wD[tid] = bxv * byv;
    }
    if (tid >= 64 && tid < 66) {
        int line = tid - 64;
        const float* ln = lines + (size_t)(L0 + line) * 4;
        float ux = ln[0], uy = ln[1], vx = ln[2], vy = ln[3];
        float dx = ux - vx, dy = uy - vy;
        float d = fmaxf(sqrtf(dx * dx + dy * dy), 1e-6f);
        s_feat[line][0] = ux * (1.0f / 128.0f);
        s_feat[line][1] = uy * (1.0f / 128.0f);
        s_feat[line][2] = vx * (1.0f / 128.0f);
        s_feat[line][3] = vy * (1.0f / 128.0f);
        s_feat[line][4] = d;
    }
    if (tid < 128) {       // zero conv2 halo rows
        int line = tid >> 6, q = tid & 63;
        s_z1[line * 720 + 0 * 72 + q] = 0;
        s_z1[line * 720 + 9 * 72 + q] = 0;
    }
    __syncthreads();

    // ---- P1: gather + bilinear + maxpool(4) -> s_xs ----
    {
        int cq = tid & 31, k = tid >> 5;     // k 0..7
        int c0 = cq * 4;
        const float* base = fmT + (size_t)b * (HH * WW * CC);
        #pragma unroll
        for (int line = 0; line < 2; ++line) {
            float4 acc;
            acc.x = -INFINITY; acc.y = -INFINITY; acc.z = -INFINITY; acc.w = -INFINITY;
            #pragma unroll
            for (int j = 0; j < 4; ++j) {
                int pt = line * 32 + k * 4 + j;
                int ix0 = s_ix0[pt], ix1 = s_ix1[pt];
                int iy0 = s_iy0[pt], iy1 = s_iy1[pt];
                float wA = s_wA[pt], wB = s_wB[pt], wC = s_wC[pt], wD = s_wD[pt];
                float4 vA = *(const float4*)(base + ((size_t)(iy0 * WW + ix0)) * CC + c0);
                float4 vB = *(const float4*)(base + ((size_t)(iy1 * WW + ix0)) * CC + c0);
                float4 vC = *(const float4*)(base + ((size_t)(iy0 * WW + ix1)) * CC + c0);
                float4 vD = *(const float4*)(base + ((size_t)(iy1 * WW + ix1)) * CC + c0);
                float4 v;
                v.x = wA * vA.x + wB * vB.x + wC * vC.x + wD * vD.x;
                v.y = wA * vA.y + wB * vB.y + wC * vC.y + wD * vD.y;
                v.z = wA * vA.z + wB * vB.z + wC * vC.z + wD * vD.z;
                v.w = wA * vA.w + wB * vB.w + wC * vC.w + wD * vD.w;
                acc.x = fmaxf(acc.x, v.x); acc.y = fmaxf(acc.y, v.y);
                acc.z = fmaxf(acc.z, v.z); acc.w = fmaxf(acc.w, v.w);
            }
            *(float4*)&s_xs[(line * 8 + k) * 128 + c0] = acc;
        }
    }
    __syncthreads();

    // ---- P1b: bn1 + relu + cvt bf16 -> s_ybn ----
    {
        int m = tid >> 4, c8 = (tid & 15) * 8;
        const float* xr = &s_xs[m * 128 + c8];
        float4 g0 = *(const float4*)(bn1_g + c8);
        float4 g1 = *(const float4*)(bn1_g + c8 + 4);
        float4 bb0 = *(const float4*)(bn1_b + c8);
        float4 bb1 = *(const float4*)(bn1_b + c8 + 4);
        const float* gg = (const float*)&g0;   // g0,g1 contiguous in regs? use arrays
        float gs[8] = {g0.x, g0.y, g0.z, g0.w, g1.x, g1.y, g1.z, g1.w};
        float bs[8] = {bb0.x, bb0.y, bb0.z, bb0.w, bb1.x, bb1.y, bb1.z, bb1.w};
        (void)gg;
        unsigned short* yr = &s_ybn[m * 136 + c8];
        #pragma unroll
        for (int i = 0; i < 8; ++i) {
            float v = fmaxf(xr[i] * (gs[i] * inv_s) + bs[i], 0.0f);
            yr[i] = f2bf(v);
        }
    }
    __syncthreads();

    // ---- P2: conv1 (M=16,K=128,N=64) + bn2 + relu -> s_z1 ----
    {
        int n0 = wv * 16;
        f32x4 acc = {0.f, 0.f, 0.f, 0.f};
        #pragma unroll
        for (int kc = 0; kc < 4; ++kc) {
            bf16x8 a = *(const bf16x8*)&s_ybn[l16 * 136 + kc * 32 + quad * 8];
            bf16x8 bf = *(const bf16x8*)(W1b + (n0 + l16) * 128 + kc * 32 + quad * 8);
            acc = __builtin_amdgcn_mfma_f32_16x16x32_bf16(a, bf, acc, 0, 0, 0);
        }
        int p = n0 + l16;
        float s2 = bn2_g[p] * inv_s, bb2 = bn2_b[p], cb = b1[p];
        int line = quad >> 1;
        int kbase = (quad & 1) * 4;
        #pragma unroll
        for (int r = 0; r < 4; ++r) {
            float v = fmaxf((acc[r] + cb) * s2 + bb2, 0.0f);
            s_z1[line * 720 + (kbase + r + 1) * 72 + p] = f2bf(v);
        }
    }
    __syncthreads();

    // ---- P3: conv2 (3 shifted GEMMs, M=16,K=64,N=64) + bn3 + relu -> s_z2 ----
    {
        int n0 = wv * 16;
        f32x4 acc = {0.f, 0.f, 0.f, 0.f};
        int line = l16 >> 3, k = l16 & 7;
        #pragma unroll
        for (int t = 0; t < 3; ++t) {
            const unsigned short* arow = &s_z1[line * 720 + (k + t) * 72];
            #pragma unroll
            for (int kc = 0; kc < 2; ++kc) {
                bf16x8 a = *(const bf16x8*)&arow[kc * 32 + quad * 8];
                bf16x8 bf = *(const bf16x8*)(W2b + t * 4096 + (n0 + l16) * 64 + kc * 32 + quad * 8);
                acc = __builtin_amdgcn_mfma_f32_16x16x32_bf16(a, bf, acc, 0, 0, 0);
            }
        }
        int p = n0 + l16;
        float s3 = bn3_g[p] * inv_s, bb3 = bn3_b[p], cb = b2[p];
        #pragma unroll
        for (int r = 0; r < 4; ++r) {
            float v = fmaxf((acc[r] + cb) * s3 + bb3, 0.0f);
            s_z2[(quad * 4 + r) * 72 + p] = f2bf(v);
        }
    }
    __syncthreads();

    // ---- P4: conv3 (M=16,K=64,N=128) + residual + relu + fc2 partials ----
    float p0 = 0.f, p1 = 0.f, p2 = 0.f, p3 = 0.f;
    {
        int kbase = (quad & 1) * 4;
        bf16x8 a0 = *(const bf16x8*)&s_z2[l16 * 72 + 0 * 32 + quad * 8];
        bf16x8 a1 = *(const bf16x8*)&s_z2[l16 * 72 + 1 * 32 + quad * 8];
        #pragma unroll
        for (int sub = 0; sub < 2; ++sub) {
            int n0 = wv * 32 + sub * 16;
            f32x4 acc = {0.f, 0.f, 0.f, 0.f};
            bf16x8 bf0 = *(const bf16x8*)(W3b + (n0 + l16) * 64 + 0 * 32 + quad * 8);
            bf16x8 bf1 = *(const bf16x8*)(W3b + (n0 + l16) * 64 + 1 * 32 + quad * 8);
            acc = __builtin_amdgcn_mfma_f32_16x16x32_bf16(a0, bf0, acc, 0, 0, 0);
            acc = __builtin_amdgcn_mfma_f32_16x16x32_bf16(a1, bf1, acc, 0, 0, 0);
            int c = n0 + l16;
            float cb = b3[c];
            #pragma unroll
            for (int r = 0; r < 4; ++r) {
                int m = quad * 4 + r;
                float v = fmaxf(s_xs[m * 128 + c] + acc[r] + cb, 0.0f);
                int idx = c * 8 + kbase + r;
                p0 = fmaf(v, fcw[0 * FCK + idx], p0);
                p1 = fmaf(v, fcw[1 * FCK + idx], p1);
                p2 = fmaf(v, fcw[2 * FCK + idx], p2);
                p3 = fmaf(v, fcw[3 * FCK + idx], p3);
            }
        }
    }
    // reduce within each 32-lane half (each half = one line)
    #pragma unroll
    for (int off = 16; off >= 1; off >>= 1) {
        p0 += __shfl_down(p0, off);
        p1 += __shfl_down(p1, off);
        p2 += __shfl_down(p2, off);
        p3 += __shfl_down(p3, off);
    }
    if ((lane & 31) == 0) {
        int line = lane >> 5;
        s_red[wv * 8 + line * 4 + 0] = p0;
        s_red[wv * 8 + line * 4 + 1] = p1;
        s_red[wv * 8 + line * 4 + 2] = p2;
        s_red[wv * 8 + line * 4 + 3] = p3;
    }
    __syncthreads();

    // ---- P5: finish logits + softmax ----
    if (tid < 2) {
        int line = tid;
        float lg[4];
        #pragma unroll
        for (int o = 0; o < 4; ++o) {
            lg[o] = fcb[o] + s_red[0 + line * 4 + o] + s_red[8 + line * 4 + o]
                  + s_red[16 + line * 4 + o] + s_red[24 + line * 4 + o];
        }
        #pragma unroll
        for (int j = 0; j < FDIM; ++j) {
            float fv = fmaxf(s_feat[line][j], 0.0f);
            #pragma unroll
            for (int o = 0; o < 4; ++o)
                lg[o] = fmaf(fv, fcw[o * FCK + 1024 + j], lg[o]);
        }
        float m = fmaxf(fmaxf(lg[0], lg[1]), fmaxf(lg[2], lg[3]));
        float e0 = expf(lg[0] - m), e1 = expf(lg[1] - m);
        float e2 = expf(lg[2] - m), e3 = expf(lg[3] - m);
        float inv = 1.0f / (e0 + e1 + e2 + e3);
        float* lo = out + (size_t)(L0 + line) * 4;
        lo[0] = lg[0]; lo[1] = lg[1]; lo[2] = lg[2]; lo[3] = lg[3];
        float* pr = out + (size_t)BB * NLL * 4 + (size_t)(L0 + line) * 4;
        pr[0] = e0 * inv; pr[1] = e1 * inv; pr[2] = e2 * inv; pr[3] = e3 * inv;
    }
}

// ---------------------------------------------------------------------------
// Fallback: round-1 proven VALU kernel (used only if ws_size is too small).
// ---------------------------------------------------------------------------
template<bool TRANS>
__global__ __launch_bounds__(256)
void line_kernel_v1(const float* __restrict__ fm,
                    const float* __restrict__ lines,
                    const float* __restrict__ bn1_g, const float* __restrict__ bn1_b,
                    const float* __restrict__ w1,    const float* __restrict__ b1,
                    const float* __restrict__ bn2_g, const float* __restrict__ bn2_b,
                    const float* __restrict__ w2,    const float* __restrict__ b2,
                    const float* __restrict__ bn3_g, const float* __restrict__ bn3_b,
                    const float* __restrict__ w3,    const float* __restrict__ b3,
                    const float* __restrict__ fcw,   const float* __restrict__ fcb,
                    float* __restrict__ out) {
    __shared__ int   s_ix0[32], s_ix1[32], s_iy0[32], s_iy1[32];
    __shared__ float s_wA[32], s_wB[32], s_wC[32], s_wD[32];
    __shared__ float xs [8][132];
    __shared__ float ybn[8][132];
    __shared__ float z1 [64][12];
    __shared__ float z2 [64][8];
    __shared__ float s_feat[8];
    __shared__ float s_red[16];

    const int L   = blockIdx.x;
    const int b   = L / NLL;
    const int tid = threadIdx.x;
    const float inv_s = 1.0f / sqrtf(1.0f + 1e-5f);
    const float* ln = lines + (size_t)L * 4;

    if (tid < 32) {
        float lam = (float)tid * (1.0f / 31.0f);
        float om  = 1.0f - lam;
        float px = ln[0] * lam + ln[2] * om - 0.5f;
        float py = ln[1] * lam + ln[3] * om - 0.5f;
        float px0 = fminf(fmaxf(floorf(px), 0.0f), 127.0f);
        float py0 = fminf(fmaxf(floorf(py), 0.0f), 127.0f);
        float px1 = fminf(px0 + 1.0f, 127.0f);
        float py1 = fminf(py0 + 1.0f, 127.0f);
        s_ix0[tid] = (int)px0; s_ix1[tid] = (int)px1;
        s_iy0[tid] = (int)py0; s_iy1[tid] = (int)py1;
        float ax = px1 - px, bxv = px - px0, ay = py1 - py, byv = py - py0;
        s_wA[tid] = ax  * ay;  s_wB[tid] = bxv * ay;
        s_wC[tid] = ax  * byv; s_wD[tid] = bxv * byv;
    }
    if (tid == 0) {
        float ux = ln[0], uy = ln[1], vx = ln[2], vy = ln[3];
        float dx = ux - vx, dy = uy - vy;
        float d = fmaxf(sqrtf(dx * dx + dy * dy), 1e-6f);
        s_feat[0] = ux / 128.0f; s_feat[1] = uy / 128.0f;
        s_feat[2] = vx / 128.0f; s_feat[3] = vy / 128.0f;
        s_feat[4] = d;
    }
    __syncthreads();
    {
        int cq = tid & 31, k = tid >> 5, c0 = cq * 4;
        float4 acc;
        acc.x = -INFINITY; acc.y = -INFINITY; acc.z = -INFINITY; acc.w = -INFINITY;
        #pragma unroll
        for (int j = 0; j < 4; ++j) {
            int pt = k * 4 + j;
            int ix0 = s_ix0[pt], ix1 = s_ix1[pt];
            int iy0 = s_iy0[pt], iy1 = s_iy1[pt];
            float wA = s_wA[pt], wB = s_wB[pt], wC = s_wC[pt], wD = s_wD[pt];
            float4 vA, vB, vC, vD;
            if (TRANS) {
                const float* base = fm + (size_t)b * HH * WW * CC;
                vA = *(const float4*)(base + ((size_t)(iy0 * WW + ix0)) * CC + c0);
                vB = *(const float4*)(base + ((size_t)(iy1 * WW + ix0)) * CC + c0);
                vC = *(const float4*)(base + ((size_t)(iy0 * WW + ix1)) * CC + c0);
                vD = *(const float4*)(base + ((size_t)(iy1 * WW + ix1)) * CC + c0);
            } else {
                const float* base = fm + ((size_t)b * CC + c0) * HH * WW;
                int oA = iy0 * WW + ix0, oB = iy1 * WW + ix0;
                int oC = iy0 * WW + ix1, oD = iy1 * WW + ix1;
                vA.x = base[oA];           vB.x = base[oB];
                vC.x = base[oC];           vD.x = base[oD];
                vA.y = base[HH*WW + oA];   vB.y = base[HH*WW + oB];
                vC.y = base[HH*WW + oC];   vD.y = base[HH*WW + oD];
                vA.z = base[2*HH*WW + oA]; vB.z = base[2*HH*WW + oB];
                vC.z = base[2*HH*WW + oC]; vD.z = base[2*HH*WW + oD];
                vA.w = base[3*HH*WW + oA]; vB.w = base[3*HH*WW + oB];
                vC.w = base[3*HH*WW + oC]; vD.w = base[3*HH*WW + oD];
            }
            float4 v;
            v.x = wA * vA.x + wB * vB.x + wC * vC.x + wD * vD.x;
            v.y = wA * vA.y + wB * vB.y + wC * vC.y + wD * vD.y;
            v.z = wA * vA.z + wB * vB.z + wC * vC.z + wD * vD.z;
            v.w = wA * vA.w + wB * vB.w + wC * vC.w + wD * vD.w;
            acc.x = fmaxf(acc.x, v.x); acc.y = fmaxf(acc.y, v.y);
            acc.z = fmaxf(acc.z, v.z); acc.w = fmaxf(acc.w, v.w);
        }
        *(float4*)(&xs[k][c0]) = acc;
    }
    __syncthreads();
    for (int e = tid; e < 1024; e += 256) {
        int k = e >> 7, c = e & 127;
        ybn[k][c] = fmaxf(xs[k][c] * (bn1_g[c] * inv_s) + bn1_b[c], 0.0f);
    }
    __syncthreads();
    if (tid < 64) { z1[tid][0] = 0.0f; z1[tid][9] = 0.0f; }
    {
        int p = tid >> 2, kq = tid & 3;
        const float* wrow = w1 + p * 128;
        float a0a = 0.f, a0b = 0.f, a1a = 0.f, a1b = 0.f;
        #pragma unroll 8
        for (int c = 0; c < 128; c += 4) {
            float4 w  = *(const float4*)(wrow + c);
            float4 ya = *(const float4*)(&ybn[kq][c]);
            float4 yb = *(const float4*)(&ybn[kq + 4][c]);
            a0a = fmaf(w.x, ya.x, a0a); a0b = fmaf(w.y, ya.y, a0b);
            a0a = fmaf(w.z, ya.z, a0a); a0b = fmaf(w.w, ya.w, a0b);
            a1a = fmaf(w.x, yb.x, a1a); a1b = fmaf(w.y, yb.y, a1b);
            a1a = fmaf(w.z, yb.z, a1a); a1b = fmaf(w.w, yb.w, a1b);
        }
        float s2 = bn2_g[p] * inv_s, bb = bn2_b[p], cb = b1[p];
        z1[p][1 + kq]     = fmaxf((a0a + a0b + cb) * s2 + bb, 0.0f);
        z1[p][1 + kq + 4] = fmaxf((a1a + a1b + cb) * s2 + bb, 0.0f);
    }
    __syncthreads();
    {
        int p = tid >> 2, kq = tid & 3;
        const float* wrow = w2 + p * 192;
        float acc0 = 0.f, acc1 = 0.f;
        #pragma unroll 4
        for (int q = 0; q < 64; ++q) {
            float w0 = wrow[q * 3 + 0], w1v = wrow[q * 3 + 1], w2v = wrow[q * 3 + 2];
            const float* zr = &z1[q][0];
            acc0 = fmaf(w0, zr[kq], acc0);
            acc0 = fmaf(w1v, zr[kq + 1], acc0);
            acc0 = fmaf(w2v, zr[kq + 2], acc0);
            acc1 = fmaf(w0, zr[kq + 4], acc1);
            acc1 = fmaf(w1v, zr[kq + 5], acc1);
            acc1 = fmaf(w2v, zr[kq + 6], acc1);
        }
        float s3 = bn3_g[p] * inv_s, bb = bn3_b[p], cb = b2[p];
        z2[p][kq]     = fmaxf((acc0 + cb) * s3 + bb, 0.0f);
        z2[p][kq + 4] = fmaxf((acc1 + cb) * s3 + bb, 0.0f);
    }
    __syncthreads();
    float part0 = 0.f, part1 = 0.f, part2 = 0.f, part3 = 0.f;
    {
        int c = tid >> 1, kq = tid & 1;
        const float* wrow = w3 + c * 64;
        float acc[4] = {0.f, 0.f, 0.f, 0.f};
        #pragma unroll 8
        for (int q = 0; q < 64; ++q) {
            float w = wrow[q];
            acc[0] = fmaf(w, z2[q][kq], acc[0]);
            acc[1] = fmaf(w, z2[q][kq + 2], acc[1]);
            acc[2] = fmaf(w, z2[q][kq + 4], acc[2]);
            acc[3] = fmaf(w, z2[q][kq + 6], acc[3]);
        }
        float cb = b3[c];
        #pragma unroll
        for (int i = 0; i < 4; ++i) {
            int k = kq + 2 * i;
            float v = fmaxf(xs[k][c] + acc[i] + cb, 0.0f);
            int idx = c * 8 + k;
            part0 = fmaf(v, fcw[0 * FCK + idx], part0);
            part1 = fmaf(v, fcw[1 * FCK + idx], part1);
            part2 = fmaf(v, fcw[2 * FCK + idx], part2);
            part3 = fmaf(v, fcw[3 * FCK + idx], part3);
        }
    }
    #pragma unroll
    for (int off = 32; off > 0; off >>= 1) {
        part0 += __shfl_down(part0, off);
        part1 += __shfl_down(part1, off);
        part2 += __shfl_down(part2, off);
        part3 += __shfl_down(part3, off);
    }
    if ((tid & 63) == 0) {
        int w = tid >> 6;
        s_red[w * 4 + 0] = part0; s_red[w * 4 + 1] = part1;
        s_red[w * 4 + 2] = part2; s_red[w * 4 + 3] = part3;
    }
    __syncthreads();
    if (tid == 0) {
        float lg[4];
        #pragma unroll
        for (int o = 0; o < 4; ++o)
            lg[o] = fcb[o] + s_red[o] + s_red[4 + o] + s_red[8 + o] + s_red[12 + o];
        #pragma unroll
        for (int j = 0; j < FDIM; ++j) {
            float fv = fmaxf(s_feat[j], 0.0f);
            #pragma unroll
            for (int o = 0; o < 4; ++o)
                lg[o] = fmaf(fv, fcw[o * FCK + 1024 + j], lg[o]);
        }
        float m = fmaxf(fmaxf(lg[0], lg[1]), fmaxf(lg[2], lg[3]));
        float e0 = expf(lg[0] - m), e1 = expf(lg[1] - m);
        float e2 = expf(lg[2] - m), e3 = expf(lg[3] - m);
        float inv = 1.0f / (e0 + e1 + e2 + e3);
        float* lo = out + (size_t)L * 4;
        lo[0] = lg[0]; lo[1] = lg[1]; lo[2] = lg[2]; lo[3] = lg[3];
        float* pr = out + (size_t)BB * NLL * 4 + (size_t)L * 4;
        pr[0] = e0 * inv; pr[1] = e1 * inv; pr[2] = e2 * inv; pr[3] = e3 * inv;
    }
}

extern "C" void kernel_launch(void* const* d_in, const int* in_sizes, int n_in,
                              void* d_out, int out_size, void* d_ws, size_t ws_size,
                              hipStream_t stream) {
    const float* fm     = (const float*)d_in[0];
    const float* lines  = (const float*)d_in[1];
    const float* bn1_g  = (const float*)d_in[2];
    const float* bn1_b  = (const float*)d_in[3];
    const float* w1     = (const float*)d_in[4];
    const float* b1     = (const float*)d_in[5];
    const float* bn2_g  = (const float*)d_in[6];
    const float* bn2_b  = (const float*)d_in[7];
    const float* w2     = (const float*)d_in[8];
    const float* b2     = (const float*)d_in[9];
    const float* bn3_g  = (const float*)d_in[10];
    const float* bn3_b  = (const float*)d_in[11];
    const float* w3     = (const float*)d_in[12];
    const float* b3     = (const float*)d_in[13];
    const float* fcw    = (const float*)d_in[14];
    const float* fcb    = (const float*)d_in[15];
    float* out = (float*)d_out;

    const size_t fmT_bytes = (size_t)BB * HH * WW * CC * sizeof(float);   // 32 MiB
    const size_t wb_bytes  = 57344;                                        // 16K+24K+16K bf16

    if (ws_size >= fmT_bytes + wb_bytes) {
        float* fmT = (float*)d_ws;
        unsigned short* W1b = (unsigned short*)((char*)d_ws + fmT_bytes);
        unsigned short* W2b = W1b + 8192;
        unsigned short* W3b = W2b + 12288;
        dim3 tg(CC / 32, BB * HH);
        transpose_fm2<<<tg, 256, 0, stream>>>(fm, fmT);
        prep_weights<<<112, 256, 0, stream>>>(w1, w2, w3, W1b, W2b, W3b);
        line_mfma<<<BB * NLL / 2, 256, 0, stream>>>(
            fmT, lines, bn1_g, bn1_b, W1b, b1, bn2_g, bn2_b, W2b, b2,
            bn3_g, bn3_b, W3b, b3, fcw, fcb, out);
    } else if (ws_size >= fmT_bytes) {
        float* fmT = (float*)d_ws;
        dim3 tg(CC / 32, BB * HH);
        transpose_fm2<<<tg, 256, 0, stream>>>(fm, fmT);
        line_kernel_v1<true><<<BB * NLL, 256, 0, stream>>>(
            fmT, lines, bn1_g, bn1_b, w1, b1, bn2_g, bn2_b, w2, b2,
            bn3_g, bn3_b, w3, b3, fcw, fcb, out);
    } else {
        line_kernel_v1<false><<<BB * NLL, 256, 0, stream>>>(
            fm, lines, bn1_g, bn1_b, w1, b1, bn2_g, bn2_b, w2, b2,
            bn3_g, bn3_b, w3, b3, fcw, fcb, out);
    }
}

// Round 3
// 154.301 us; speedup vs baseline: 1.7177x; 1.0849x over previous
//
#include <hip/hip_runtime.h>
#include <math.h>

#define BB 4
#define NLL 2048
#define CC 128
#define HH 128
#define WW 128
#define NPTS0 32
#define NPTS1 8
#define PP 64
#define FDIM 5
#define FCK (CC*NPTS1 + FDIM)   // 1029

typedef __attribute__((ext_vector_type(8))) short bf16x8;
typedef __attribute__((ext_vector_type(4))) float f32x4;

__device__ __forceinline__ unsigned short f2bf(float f) {
    union { float f; unsigned u; } v; v.f = f;
    unsigned u = v.u;
    return (unsigned short)((u + 0x7fffu + ((u >> 16) & 1u)) >> 16);
}
__device__ __forceinline__ float bf2f(unsigned short s) {
    union { unsigned u; float f; } v; v.u = ((unsigned)s) << 16;
    return v.f;
}

// ---------------------------------------------------------------------------
// Transpose v3: (B,C,H,W) fp32 -> (B,H,W,C) bf16. One block per (b,y,x-half).
// LDS tile [c][x] (64 cols, stride 72) with XOR-4 swizzle on x to keep both
// sides near-conflict-free. Reads 512B/row chunks; writes 256B-contiguous.
// ---------------------------------------------------------------------------
__global__ __launch_bounds__(256)
void transpose_fm3(const float* __restrict__ fm, unsigned short* __restrict__ fmT) {
    __shared__ unsigned short tile[128 * 72];
    const int by = blockIdx.x >> 1;       // b*H + y
    const int xh = blockIdx.x & 1;        // x half (64 cols)
    const int b = by >> 7, y = by & 127;
    const int t = threadIdx.x;
    const float* src = fm + ((size_t)b * CC) * (HH * WW) + (size_t)y * WW + xh * 64;
    const int x4 = (t & 15) * 4;
    const int r0 = t >> 4;                // 0..15
    #pragma unroll
    for (int i = 0; i < 8; ++i) {
        int r = r0 + 16 * i;              // channel
        float4 v = *(const float4*)&src[(size_t)r * (HH * WW) + x4];
        ushort4 u;
        u.x = f2bf(v.x); u.y = f2bf(v.y); u.z = f2bf(v.z); u.w = f2bf(v.w);
        *(ushort4*)&tile[r * 72 + (x4 ^ (r & 28))] = u;
    }
    __syncthreads();
    unsigned short* dst = fmT + ((size_t)by * WW + xh * 64) * CC;
    const int c4 = (t & 31) * 4;
    #pragma unroll
    for (int i = 0; i < 8; ++i) {
        int x = (t >> 5) + 8 * i;         // 0..63
        ushort4 u;
        u.x = tile[(c4 + 0) * 72 + (x ^ ((c4 + 0) & 28))];
        u.y = tile[(c4 + 1) * 72 + (x ^ ((c4 + 1) & 28))];
        u.z = tile[(c4 + 2) * 72 + (x ^ ((c4 + 2) & 28))];
        u.w = tile[(c4 + 3) * 72 + (x ^ ((c4 + 3) & 28))];
        *(ushort4*)&dst[(size_t)x * CC + c4] = u;   // 32 lanes -> 256B contiguous
    }
}

// ---------------------------------------------------------------------------
// Weight prep: fp32 -> bf16, B-operand [n][k] row-major.
// ---------------------------------------------------------------------------
__global__ __launch_bounds__(256)
void prep_weights(const float* __restrict__ w1, const float* __restrict__ w2,
                  const float* __restrict__ w3, unsigned short* __restrict__ W1b,
                  unsigned short* __restrict__ W2b, unsigned short* __restrict__ W3b) {
    int gid = blockIdx.x * 256 + threadIdx.x;
    if (gid < 8192) {
        W1b[gid] = f2bf(w1[gid]);
    } else if (gid < 20480) {
        int g = gid - 8192;
        int tt = g >> 12, r = g & 4095;
        int p = r >> 6, q = r & 63;
        W2b[tt * 4096 + p * 64 + q] = f2bf(w2[p * 192 + q * 3 + tt]);
    } else if (gid < 28672) {
        int g = gid - 20480;
        W3b[g] = f2bf(w3[g]);
    }
}

// ---------------------------------------------------------------------------
// Fused line pipeline, MFMA + bf16-gather version. 2 lines/block, 256 thr.
// MFMA 16x16x32 bf16 mapping: A[m=lane&15][k=quad*8+j], C/D col=lane&15,
// row=quad*4+reg.
// ---------------------------------------------------------------------------
__global__ __launch_bounds__(256)
void line_mfma(const unsigned short* __restrict__ fmT,   // (B,H,W,C) bf16
               const float* __restrict__ lines,
               const float* __restrict__ bn1_g, const float* __restrict__ bn1_b,
               const unsigned short* __restrict__ W1b, const float* __restrict__ b1,
               const float* __restrict__ bn2_g, const float* __restrict__ bn2_b,
               const unsigned short* __restrict__ W2b, const float* __restrict__ b2,
               const float* __restrict__ bn3_g, const float* __restrict__ bn3_b,
               const unsigned short* __restrict__ W3b, const float* __restrict__ b3,
               const float* __restrict__ fcw,   const float* __restrict__ fcb,
               float* __restrict__ out) {
    __shared__ int   s_oA[64], s_oB[64], s_oC[64], s_oD[64];   // element offsets
    __shared__ float s_wA[64], s_wB[64], s_wC[64], s_wD[64];
    __shared__ float s_xs[16 * 128];             // residual, fp32, [m][c]
    __shared__ unsigned short s_ybn[16 * 136];   // relu(bn1), bf16, [m][c]
    __shared__ unsigned short s_z1[2 * 10 * 72]; // conv1 out, halo rows 0/9 zero
    __shared__ unsigned short s_z2[16 * 72];     // conv2 out, [m][q]
    __shared__ float s_feat[2][8];
    __shared__ float s_red[4 * 8];

    const int bx  = blockIdx.x;
    const int L0  = bx * 2;
    const int b   = bx >> 10;
    const int tid = threadIdx.x;
    const int lane = tid & 63;
    const int wv   = tid >> 6;
    const int quad = lane >> 4;
    const int l16  = lane & 15;
    const float inv_s = 1.0f / sqrtf(1.0f + 1e-5f);

    // ---- P0: per-point offsets/weights, line features, halo zeroing ----
    if (tid < 64) {
        int line = tid >> 5, pt = tid & 31;
        const float* ln = lines + (size_t)(L0 + line) * 4;
        float lam = (float)pt * (1.0f / 31.0f);
        float om  = 1.0f - lam;
        float px = ln[0] * lam + ln[2] * om - 0.5f;
        float py = ln[1] * lam + ln[3] * om - 0.5f;
        float px0 = fminf(fmaxf(floorf(px), 0.0f), 127.0f);
        float py0 = fminf(fmaxf(floorf(py), 0.0f), 127.0f);
        float px1 = fminf(px0 + 1.0f, 127.0f);
        float py1 = fminf(py0 + 1.0f, 127.0f);
        int ix0 = (int)px0, ix1 = (int)px1, iy0 = (int)py0, iy1 = (int)py1;
        s_oA[tid] = (iy0 * WW + ix0) * CC;
        s_oB[tid] = (iy1 * WW + ix0) * CC;
        s_oC[tid] = (iy0 * WW + ix1) * CC;
        s_oD[tid] = (iy1 * WW + ix1) * CC;
        float ax = px1 - px, bxv = px - px0, ay = py1 - py, byv = py - py0;
        // exact reference pairing (its bilinear weights are x/y-swapped)
        s_wA[tid] = ax  * ay;
        s_wB[tid] = bxv * ay;
        s_wC[tid] = ax  * byv;
        s_wD[tid] = bxv * byv;
    }
    if (tid >= 64 && tid < 66) {
        int line = tid - 64;
        const float* ln = lines + (size_t)(L0 + line) * 4;
        float ux = ln[0], uy = ln[1], vx = ln[2], vy = ln[3];
        float dx = ux - vx, dy = uy - vy;
        float d = fmaxf(sqrtf(dx * dx + dy * dy), 1e-6f);
        s_feat[line][0] = ux * (1.0f / 128.0f);
        s_feat[line][1] = uy * (1.0f / 128.0f);
        s_feat[line][2] = vx * (1.0f / 128.0f);
        s_feat[line][3] = vy * (1.0f / 128.0f);
        s_feat[line][4] = d;
    }
    if (tid < 128) {
        int line = tid >> 6, q = tid & 63;
        s_z1[line * 720 + 0 * 72 + q] = 0;
        s_z1[line * 720 + 9 * 72 + q] = 0;
    }
    __syncthreads();

    // ---- P1: bf16 gather + bilinear + maxpool(4) -> s_xs (fp32) ----
    {
        int tl = tid >> 4;               // 0..15 = line*8 + k
        int line = tl >> 3, k = tl & 7;
        int c8 = (tid & 15) * 8;
        const unsigned short* base = fmT + (size_t)b * (HH * WW * CC) + c8;
        float acc[8];
        #pragma unroll
        for (int i = 0; i < 8; ++i) acc[i] = -INFINITY;
        #pragma unroll
        for (int j = 0; j < 4; ++j) {
            int pt = line * 32 + k * 4 + j;
            bf16x8 rA = *(const bf16x8*)(base + s_oA[pt]);
            bf16x8 rB = *(const bf16x8*)(base + s_oB[pt]);
            bf16x8 rC = *(const bf16x8*)(base + s_oC[pt]);
            bf16x8 rD = *(const bf16x8*)(base + s_oD[pt]);
            float wA = s_wA[pt], wB = s_wB[pt], wC = s_wC[pt], wD = s_wD[pt];
            #pragma unroll
            for (int i = 0; i < 8; ++i) {
                float v = wA * bf2f((unsigned short)rA[i])
                        + wB * bf2f((unsigned short)rB[i])
                        + wC * bf2f((unsigned short)rC[i])
                        + wD * bf2f((unsigned short)rD[i]);
                acc[i] = fmaxf(acc[i], v);
            }
        }
        float* xr = &s_xs[tl * 128 + c8];
        #pragma unroll
        for (int i = 0; i < 8; ++i) xr[i] = acc[i];
    }
    __syncthreads();

    // ---- P1b: bn1 + relu + cvt bf16 -> s_ybn (vectorized b128 store) ----
    {
        int m = tid >> 4, c8 = (tid & 15) * 8;
        const float* xr = &s_xs[m * 128 + c8];
        bf16x8 pack;
        #pragma unroll
        for (int i = 0; i < 8; ++i) {
            float v = fmaxf(xr[i] * (bn1_g[c8 + i] * inv_s) + bn1_b[c8 + i], 0.0f);
            pack[i] = (short)f2bf(v);
        }
        *(bf16x8*)&s_ybn[m * 136 + c8] = pack;
    }
    __syncthreads();

    // ---- P2: conv1 (M=16,K=128,N=64) + bn2 + relu -> s_z1 ----
    {
        int n0 = wv * 16;
        f32x4 acc = {0.f, 0.f, 0.f, 0.f};
        #pragma unroll
        for (int kc = 0; kc < 4; ++kc) {
            bf16x8 a = *(const bf16x8*)&s_ybn[l16 * 136 + kc * 32 + quad * 8];
            bf16x8 bf = *(const bf16x8*)(W1b + (n0 + l16) * 128 + kc * 32 + quad * 8);
            acc = __builtin_amdgcn_mfma_f32_16x16x32_bf16(a, bf, acc, 0, 0, 0);
        }
        int p = n0 + l16;
        float s2 = bn2_g[p] * inv_s, bb2 = bn2_b[p], cb = b1[p];
        int line = quad >> 1;
        int kbase = (quad & 1) * 4;
        #pragma unroll
        for (int r = 0; r < 4; ++r) {
            float v = fmaxf((acc[r] + cb) * s2 + bb2, 0.0f);
            s_z1[line * 720 + (kbase + r + 1) * 72 + p] = f2bf(v);
        }
    }
    __syncthreads();

    // ---- P3: conv2 (3 shifted GEMMs, M=16,K=64,N=64) + bn3 + relu -> s_z2 ----
    {
        int n0 = wv * 16;
        f32x4 acc = {0.f, 0.f, 0.f, 0.f};
        int line = l16 >> 3, k = l16 & 7;
        #pragma unroll
        for (int t = 0; t < 3; ++t) {
            const unsigned short* arow = &s_z1[line * 720 + (k + t) * 72];
            #pragma unroll
            for (int kc = 0; kc < 2; ++kc) {
                bf16x8 a = *(const bf16x8*)&arow[kc * 32 + quad * 8];
                bf16x8 bf = *(const bf16x8*)(W2b + t * 4096 + (n0 + l16) * 64 + kc * 32 + quad * 8);
                acc = __builtin_amdgcn_mfma_f32_16x16x32_bf16(a, bf, acc, 0, 0, 0);
            }
        }
        int p = n0 + l16;
        float s3 = bn3_g[p] * inv_s, bb3 = bn3_b[p], cb = b2[p];
        #pragma unroll
        for (int r = 0; r < 4; ++r) {
            float v = fmaxf((acc[r] + cb) * s3 + bb3, 0.0f);
            s_z2[(quad * 4 + r) * 72 + p] = f2bf(v);
        }
    }
    __syncthreads();

    // ---- P4: conv3 (M=16,K=64,N=128) + residual + relu + fc2 partials ----
    float p0 = 0.f, p1 = 0.f, p2 = 0.f, p3 = 0.f;
    {
        int kbase = (quad & 1) * 4;
        bf16x8 a0 = *(const bf16x8*)&s_z2[l16 * 72 + 0 * 32 + quad * 8];
        bf16x8 a1 = *(const bf16x8*)&s_z2[l16 * 72 + 1 * 32 + quad * 8];
        #pragma unroll
        for (int sub = 0; sub < 2; ++sub) {
            int n0 = wv * 32 + sub * 16;
            f32x4 acc = {0.f, 0.f, 0.f, 0.f};
            bf16x8 bf0 = *(const bf16x8*)(W3b + (n0 + l16) * 64 + 0 * 32 + quad * 8);
            bf16x8 bf1 = *(const bf16x8*)(W3b + (n0 + l16) * 64 + 1 * 32 + quad * 8);
            acc = __builtin_amdgcn_mfma_f32_16x16x32_bf16(a0, bf0, acc, 0, 0, 0);
            acc = __builtin_amdgcn_mfma_f32_16x16x32_bf16(a1, bf1, acc, 0, 0, 0);
            int c = n0 + l16;
            float cb = b3[c];
            #pragma unroll
            for (int r = 0; r < 4; ++r) {
                int m = quad * 4 + r;
                float v = fmaxf(s_xs[m * 128 + c] + acc[r] + cb, 0.0f);
                int idx = c * 8 + kbase + r;
                p0 = fmaf(v, fcw[0 * FCK + idx], p0);
                p1 = fmaf(v, fcw[1 * FCK + idx], p1);
                p2 = fmaf(v, fcw[2 * FCK + idx], p2);
                p3 = fmaf(v, fcw[3 * FCK + idx], p3);
            }
        }
    }
    #pragma unroll
    for (int off = 16; off >= 1; off >>= 1) {
        p0 += __shfl_down(p0, off);
        p1 += __shfl_down(p1, off);
        p2 += __shfl_down(p2, off);
        p3 += __shfl_down(p3, off);
    }
    if ((lane & 31) == 0) {
        int line = lane >> 5;
        s_red[wv * 8 + line * 4 + 0] = p0;
        s_red[wv * 8 + line * 4 + 1] = p1;
        s_red[wv * 8 + line * 4 + 2] = p2;
        s_red[wv * 8 + line * 4 + 3] = p3;
    }
    __syncthreads();

    // ---- P5: finish logits + softmax ----
    if (tid < 2) {
        int line = tid;
        float lg[4];
        #pragma unroll
        for (int o = 0; o < 4; ++o) {
            lg[o] = fcb[o] + s_red[0 + line * 4 + o] + s_red[8 + line * 4 + o]
                  + s_red[16 + line * 4 + o] + s_red[24 + line * 4 + o];
        }
        #pragma unroll
        for (int j = 0; j < FDIM; ++j) {
            float fv = fmaxf(s_feat[line][j], 0.0f);
            #pragma unroll
            for (int o = 0; o < 4; ++o)
                lg[o] = fmaf(fv, fcw[o * FCK + 1024 + j], lg[o]);
        }
        float m = fmaxf(fmaxf(lg[0], lg[1]), fmaxf(lg[2], lg[3]));
        float e0 = expf(lg[0] - m), e1 = expf(lg[1] - m);
        float e2 = expf(lg[2] - m), e3 = expf(lg[3] - m);
        float inv = 1.0f / (e0 + e1 + e2 + e3);
        float* lo = out + (size_t)(L0 + line) * 4;
        lo[0] = lg[0]; lo[1] = lg[1]; lo[2] = lg[2]; lo[3] = lg[3];
        float* pr = out + (size_t)BB * NLL * 4 + (size_t)(L0 + line) * 4;
        pr[0] = e0 * inv; pr[1] = e1 * inv; pr[2] = e2 * inv; pr[3] = e3 * inv;
    }
}

// ---------------------------------------------------------------------------
// Fallback: round-1 proven VALU kernel + fp32 transpose (small-ws paths).
// ---------------------------------------------------------------------------
__global__ __launch_bounds__(256)
void transpose_fm2(const float* __restrict__ fm, float* __restrict__ fmT) {
    __shared__ float tile[32 * 132];
    const int c0 = blockIdx.x * 32;
    const int by = blockIdx.y;
    const int b = by >> 7, y = by & 127;
    const int t = threadIdx.x;
    const float* src = fm + ((size_t)b * CC) * (HH * WW) + (size_t)y * WW;
    const int x4 = (t & 31) * 4;
    #pragma unroll
    for (int i = 0; i < 4; ++i) {
        int r = (t >> 5) + 8 * i;
        *(float4*)&tile[r * 132 + x4] =
            *(const float4*)&src[(size_t)(c0 + r) * (HH * WW) + x4];
    }
    __syncthreads();
    float* dst = fmT + (size_t)by * WW * CC + c0 + (t & 31);
    const int cr = (t & 31) * 132;
    #pragma unroll
    for (int i = 0; i < 16; ++i) {
        int x = (t >> 5) + 8 * i;
        dst[(size_t)x * CC] = tile[cr + x];
    }
}

template<bool TRANS>
__global__ __launch_bounds__(256)
void line_kernel_v1(const float* __restrict__ fm,
                    const float* __restrict__ lines,
                    const float* __restrict__ bn1_g, const float* __restrict__ bn1_b,
                    const float* __restrict__ w1,    const float* __restrict__ b1,
                    const float* __restrict__ bn2_g, const float* __restrict__ bn2_b,
                    const float* __restrict__ w2,    const float* __restrict__ b2,
                    const float* __restrict__ bn3_g, const float* __restrict__ bn3_b,
                    const float* __restrict__ w3,    const float* __restrict__ b3,
                    const float* __restrict__ fcw,   const float* __restrict__ fcb,
                    float* __restrict__ out) {
    __shared__ int   s_ix0[32], s_ix1[32], s_iy0[32], s_iy1[32];
    __shared__ float s_wA[32], s_wB[32], s_wC[32], s_wD[32];
    __shared__ float xs [8][132];
    __shared__ float ybn[8][132];
    __shared__ float z1 [64][12];
    __shared__ float z2 [64][8];
    __shared__ float s_feat[8];
    __shared__ float s_red[16];

    const int L   = blockIdx.x;
    const int b   = L / NLL;
    const int tid = threadIdx.x;
    const float inv_s = 1.0f / sqrtf(1.0f + 1e-5f);
    const float* ln = lines + (size_t)L * 4;

    if (tid < 32) {
        float lam = (float)tid * (1.0f / 31.0f);
        float om  = 1.0f - lam;
        float px = ln[0] * lam + ln[2] * om - 0.5f;
        float py = ln[1] * lam + ln[3] * om - 0.5f;
        float px0 = fminf(fmaxf(floorf(px), 0.0f), 127.0f);
        float py0 = fminf(fmaxf(floorf(py), 0.0f), 127.0f);
        float px1 = fminf(px0 + 1.0f, 127.0f);
        float py1 = fminf(py0 + 1.0f, 127.0f);
        s_ix0[tid] = (int)px0; s_ix1[tid] = (int)px1;
        s_iy0[tid] = (int)py0; s_iy1[tid] = (int)py1;
        float ax = px1 - px, bxv = px - px0, ay = py1 - py, byv = py - py0;
        s_wA[tid] = ax  * ay;  s_wB[tid] = bxv * ay;
        s_wC[tid] = ax  * byv; s_wD[tid] = bxv * byv;
    }
    if (tid == 0) {
        float ux = ln[0], uy = ln[1], vx = ln[2], vy = ln[3];
        float dx = ux - vx, dy = uy - vy;
        float d = fmaxf(sqrtf(dx * dx + dy * dy), 1e-6f);
        s_feat[0] = ux / 128.0f; s_feat[1] = uy / 128.0f;
        s_feat[2] = vx / 128.0f; s_feat[3] = vy / 128.0f;
        s_feat[4] = d;
    }
    __syncthreads();
    {
        int cq = tid & 31, k = tid >> 5, c0 = cq * 4;
        float4 acc;
        acc.x = -INFINITY; acc.y = -INFINITY; acc.z = -INFINITY; acc.w = -INFINITY;
        #pragma unroll
        for (int j = 0; j < 4; ++j) {
            int pt = k * 4 + j;
            int ix0 = s_ix0[pt], ix1 = s_ix1[pt];
            int iy0 = s_iy0[pt], iy1 = s_iy1[pt];
            float wA = s_wA[pt], wB = s_wB[pt], wC = s_wC[pt], wD = s_wD[pt];
            float4 vA, vB, vC, vD;
            if (TRANS) {
                const float* base = fm + (size_t)b * HH * WW * CC;
                vA = *(const float4*)(base + ((size_t)(iy0 * WW + ix0)) * CC + c0);
                vB = *(const float4*)(base + ((size_t)(iy1 * WW + ix0)) * CC + c0);
                vC = *(const float4*)(base + ((size_t)(iy0 * WW + ix1)) * CC + c0);
                vD = *(const float4*)(base + ((size_t)(iy1 * WW + ix1)) * CC + c0);
            } else {
                const float* base = fm + ((size_t)b * CC + c0) * HH * WW;
                int oA = iy0 * WW + ix0, oB = iy1 * WW + ix0;
                int oC = iy0 * WW + ix1, oD = iy1 * WW + ix1;
                vA.x = base[oA];           vB.x = base[oB];
                vC.x = base[oC];           vD.x = base[oD];
                vA.y = base[HH*WW + oA];   vB.y = base[HH*WW + oB];
                vC.y = base[HH*WW + oC];   vD.y = base[HH*WW + oD];
                vA.z = base[2*HH*WW + oA]; vB.z = base[2*HH*WW + oB];
                vC.z = base[2*HH*WW + oC]; vD.z = base[2*HH*WW + oD];
                vA.w = base[3*HH*WW + oA]; vB.w = base[3*HH*WW + oB];
                vC.w = base[3*HH*WW + oC]; vD.w = base[3*HH*WW + oD];
            }
            float4 v;
            v.x = wA * vA.x + wB * vB.x + wC * vC.x + wD * vD.x;
            v.y = wA * vA.y + wB * vB.y + wC * vC.y + wD * vD.y;
            v.z = wA * vA.z + wB * vB.z + wC * vC.z + wD * vD.z;
            v.w = wA * vA.w + wB * vB.w + wC * vC.w + wD * vD.w;
            acc.x = fmaxf(acc.x, v.x); acc.y = fmaxf(acc.y, v.y);
            acc.z = fmaxf(acc.z, v.z); acc.w = fmaxf(acc.w, v.w);
        }
        *(float4*)(&xs[k][c0]) = acc;
    }
    __syncthreads();
    for (int e = tid; e < 1024; e += 256) {
        int k = e >> 7, c = e & 127;
        ybn[k][c] = fmaxf(xs[k][c] * (bn1_g[c] * inv_s) + bn1_b[c], 0.0f);
    }
    __syncthreads();
    if (tid < 64) { z1[tid][0] = 0.0f; z1[tid][9] = 0.0f; }
    {
        int p = tid >> 2, kq = tid & 3;
        const float* wrow = w1 + p * 128;
        float a0a = 0.f, a0b = 0.f, a1a = 0.f, a1b = 0.f;
        #pragma unroll 8
        for (int c = 0; c < 128; c += 4) {
            float4 w  = *(const float4*)(wrow + c);
            float4 ya = *(const float4*)(&ybn[kq][c]);
            float4 yb = *(const float4*)(&ybn[kq + 4][c]);
            a0a = fmaf(w.x, ya.x, a0a); a0b = fmaf(w.y, ya.y, a0b);
            a0a = fmaf(w.z, ya.z, a0a); a0b = fmaf(w.w, ya.w, a0b);
            a1a = fmaf(w.x, yb.x, a1a); a1b = fmaf(w.y, yb.y, a1b);
            a1a = fmaf(w.z, yb.z, a1a); a1b = fmaf(w.w, yb.w, a1b);
        }
        float s2 = bn2_g[p] * inv_s, bb = bn2_b[p], cb = b1[p];
        z1[p][1 + kq]     = fmaxf((a0a + a0b + cb) * s2 + bb, 0.0f);
        z1[p][1 + kq + 4] = fmaxf((a1a + a1b + cb) * s2 + bb, 0.0f);
    }
    __syncthreads();
    {
        int p = tid >> 2, kq = tid & 3;
        const float* wrow = w2 + p * 192;
        float acc0 = 0.f, acc1 = 0.f;
        #pragma unroll 4
        for (int q = 0; q < 64; ++q) {
            float w0 = wrow[q * 3 + 0], w1v = wrow[q * 3 + 1], w2v = wrow[q * 3 + 2];
            const float* zr = &z1[q][0];
            acc0 = fmaf(w0, zr[kq], acc0);
            acc0 = fmaf(w1v, zr[kq + 1], acc0);
            acc0 = fmaf(w2v, zr[kq + 2], acc0);
            acc1 = fmaf(w0, zr[kq + 4], acc1);
            acc1 = fmaf(w1v, zr[kq + 5], acc1);
            acc1 = fmaf(w2v, zr[kq + 6], acc1);
        }
        float s3 = bn3_g[p] * inv_s, bb = bn3_b[p], cb = b2[p];
        z2[p][kq]     = fmaxf((acc0 + cb) * s3 + bb, 0.0f);
        z2[p][kq + 4] = fmaxf((acc1 + cb) * s3 + bb, 0.0f);
    }
    __syncthreads();
    float part0 = 0.f, part1 = 0.f, part2 = 0.f, part3 = 0.f;
    {
        int c = tid >> 1, kq = tid & 1;
        const float* wrow = w3 + c * 64;
        float acc[4] = {0.f, 0.f, 0.f, 0.f};
        #pragma unroll 8
        for (int q = 0; q < 64; ++q) {
            float w = wrow[q];
            acc[0] = fmaf(w, z2[q][kq], acc[0]);
            acc[1] = fmaf(w, z2[q][kq + 2], acc[1]);
            acc[2] = fmaf(w, z2[q][kq + 4], acc[2]);
            acc[3] = fmaf(w, z2[q][kq + 6], acc[3]);
        }
        float cb = b3[c];
        #pragma unroll
        for (int i = 0; i < 4; ++i) {
            int k = kq + 2 * i;
            float v = fmaxf(xs[k][c] + acc[i] + cb, 0.0f);
            int idx = c * 8 + k;
            part0 = fmaf(v, fcw[0 * FCK + idx], part0);
            part1 = fmaf(v, fcw[1 * FCK + idx], part1);
            part2 = fmaf(v, fcw[2 * FCK + idx], part2);
            part3 = fmaf(v, fcw[3 * FCK + idx], part3);
        }
    }
    #pragma unroll
    for (int off = 32; off > 0; off >>= 1) {
        part0 += __shfl_down(part0, off);
        part1 += __shfl_down(part1, off);
        part2 += __shfl_down(part2, off);
        part3 += __shfl_down(part3, off);
    }
    if ((tid & 63) == 0) {
        int w = tid >> 6;
        s_red[w * 4 + 0] = part0; s_red[w * 4 + 1] = part1;
        s_red[w * 4 + 2] = part2; s_red[w * 4 + 3] = part3;
    }
    __syncthreads();
    if (tid == 0) {
        float lg[4];
        #pragma unroll
        for (int o = 0; o < 4; ++o)
            lg[o] = fcb[o] + s_red[o] + s_red[4 + o] + s_red[8 + o] + s_red[12 + o];
        #pragma unroll
        for (int j = 0; j < FDIM; ++j) {
            float fv = fmaxf(s_feat[j], 0.0f);
            #pragma unroll
            for (int o = 0; o < 4; ++o)
                lg[o] = fmaf(fv, fcw[o * FCK + 1024 + j], lg[o]);
        }
        float m = fmaxf(fmaxf(lg[0], lg[1]), fmaxf(lg[2], lg[3]));
        float e0 = expf(lg[0] - m), e1 = expf(lg[1] - m);
        float e2 = expf(lg[2] - m), e3 = expf(lg[3] - m);
        float inv = 1.0f / (e0 + e1 + e2 + e3);
        float* lo = out + (size_t)L * 4;
        lo[0] = lg[0]; lo[1] = lg[1]; lo[2] = lg[2]; lo[3] = lg[3];
        float* pr = out + (size_t)BB * NLL * 4 + (size_t)L * 4;
        pr[0] = e0 * inv; pr[1] = e1 * inv; pr[2] = e2 * inv; pr[3] = e3 * inv;
    }
}

extern "C" void kernel_launch(void* const* d_in, const int* in_sizes, int n_in,
                              void* d_out, int out_size, void* d_ws, size_t ws_size,
                              hipStream_t stream) {
    const float* fm     = (const float*)d_in[0];
    const float* lines  = (const float*)d_in[1];
    const float* bn1_g  = (const float*)d_in[2];
    const float* bn1_b  = (const float*)d_in[3];
    const float* w1     = (const float*)d_in[4];
    const float* b1     = (const float*)d_in[5];
    const float* bn2_g  = (const float*)d_in[6];
    const float* bn2_b  = (const float*)d_in[7];
    const float* w2     = (const float*)d_in[8];
    const float* b2     = (const float*)d_in[9];
    const float* bn3_g  = (const float*)d_in[10];
    const float* bn3_b  = (const float*)d_in[11];
    const float* w3     = (const float*)d_in[12];
    const float* b3     = (const float*)d_in[13];
    const float* fcw    = (const float*)d_in[14];
    const float* fcb    = (const float*)d_in[15];
    float* out = (float*)d_out;

    const size_t fmTb_bytes = (size_t)BB * HH * WW * CC * sizeof(unsigned short); // 8 MiB
    const size_t fmTf_bytes = (size_t)BB * HH * WW * CC * sizeof(float);          // 32 MiB
    const size_t wb_bytes   = 57344;

    if (ws_size >= fmTb_bytes + wb_bytes) {
        unsigned short* fmT = (unsigned short*)d_ws;
        unsigned short* W1b = (unsigned short*)((char*)d_ws + fmTb_bytes);
        unsigned short* W2b = W1b + 8192;
        unsigned short* W3b = W2b + 12288;
        prep_weights<<<112, 256, 0, stream>>>(w1, w2, w3, W1b, W2b, W3b);
        transpose_fm3<<<BB * HH * 2, 256, 0, stream>>>(fm, fmT);
        line_mfma<<<BB * NLL / 2, 256, 0, stream>>>(
            fmT, lines, bn1_g, bn1_b, W1b, b1, bn2_g, bn2_b, W2b, b2,
            bn3_g, bn3_b, W3b, b3, fcw, fcb, out);
    } else if (ws_size >= fmTf_bytes) {
        float* fmT = (float*)d_ws;
        dim3 tg(CC / 32, BB * HH);
        transpose_fm2<<<tg, 256, 0, stream>>>(fm, fmT);
        line_kernel_v1<true><<<BB * NLL, 256, 0, stream>>>(
            fmT, lines, bn1_g, bn1_b, w1, b1, bn2_g, bn2_b, w2, b2,
            bn3_g, bn3_b, w3, b3, fcw, fcb, out);
    } else {
        line_kernel_v1<false><<<BB * NLL, 256, 0, stream>>>(
            fm, lines, bn1_g, bn1_b, w1, b1, bn2_g, bn2_b, w2, b2,
            bn3_g, bn3_b, w3, b3, fcw, fcb, out);
    }
}

// Round 4
// 149.788 us; speedup vs baseline: 1.7695x; 1.0301x over previous
//
#include <hip/hip_runtime.h>
#include <math.h>

#define BB 4
#define NLL 2048
#define CC 128
#define HH 128
#define WW 128
#define NPTS0 32
#define NPTS1 8
#define PP 64
#define FDIM 5
#define FCK (CC*NPTS1 + FDIM)   // 1029
#define FCKP 1032               // padded stride for aligned float4 loads

typedef __attribute__((ext_vector_type(8))) short bf16x8;
typedef __attribute__((ext_vector_type(4))) float f32x4;

__device__ __forceinline__ unsigned short f2bf(float f) {
    union { float f; unsigned u; } v; v.f = f;
    unsigned u = v.u;
    return (unsigned short)((u + 0x7fffu + ((u >> 16) & 1u)) >> 16);
}
__device__ __forceinline__ float bf2f(unsigned short s) {
    union { unsigned u; float f; } v; v.u = ((unsigned)s) << 16;
    return v.f;
}

// ---------------------------------------------------------------------------
// Transpose v4 + fused weight prep.
// Blocks [0,512): one block per (b,y). Reads full 512B row segments (fp32),
// converts to bf16, stages in two 64-wide XOR-swizzled tiles, writes
// 256B-contiguous (x,c) chunks.
// Blocks [512,528): convert conv weights to bf16 [n][k] layouts + build
// padded fcwP[4][1032] fp32.
// ---------------------------------------------------------------------------
__global__ __launch_bounds__(256)
void transpose_prep(const float* __restrict__ fm, const float* __restrict__ w1,
                    const float* __restrict__ w2, const float* __restrict__ w3,
                    const float* __restrict__ fcw,
                    unsigned short* __restrict__ fmT,
                    unsigned short* __restrict__ W1b,
                    unsigned short* __restrict__ W2b,
                    unsigned short* __restrict__ W3b,
                    float* __restrict__ fcwP) {
    const int t = threadIdx.x;
    if (blockIdx.x >= 512) {
        int gid = (blockIdx.x - 512) * 256 + t;
        for (int e = gid; e < 32800; e += 4096) {
            if (e < 8192) {
                W1b[e] = f2bf(w1[e]);
            } else if (e < 20480) {
                int g = e - 8192;
                int tt = g >> 12, r = g & 4095;
                int p = r >> 6, q = r & 63;
                W2b[tt * 4096 + p * 64 + q] = f2bf(w2[p * 192 + q * 3 + tt]);
            } else if (e < 28672) {
                int g = e - 20480;
                W3b[g] = f2bf(w3[g]);
            } else {
                int g = e - 28672;              // 0..4127
                int o = g / FCKP, r = g - o * FCKP;
                fcwP[g] = (r < FCK) ? fcw[o * FCK + r] : 0.0f;
            }
        }
        return;
    }
    __shared__ unsigned short tile[2][128 * 72];
    const int by = blockIdx.x;            // b*H + y
    const int b = by >> 7, y = by & 127;
    const float* src = fm + ((size_t)b * CC) * (HH * WW) + (size_t)y * WW;
    const int x4 = (t & 31) * 4;          // 0..124
    const int xh = x4 >> 6, xl = x4 & 63;
    #pragma unroll
    for (int i = 0; i < 16; ++i) {
        int r = (t >> 5) + 8 * i;         // channel 0..127
        float4 v = *(const float4*)&src[(size_t)r * (HH * WW) + x4];
        ushort4 u;
        u.x = f2bf(v.x); u.y = f2bf(v.y); u.z = f2bf(v.z); u.w = f2bf(v.w);
        *(ushort4*)&tile[xh][r * 72 + (xl ^ (r & 28))] = u;
    }
    __syncthreads();
    const int c4 = (t & 31) * 4;
    #pragma unroll
    for (int h = 0; h < 2; ++h) {
        unsigned short* dst = fmT + ((size_t)by * WW + h * 64) * CC;
        #pragma unroll
        for (int i = 0; i < 8; ++i) {
            int x = (t >> 5) + 8 * i;     // 0..63
            ushort4 u;
            u.x = tile[h][(c4 + 0) * 72 + (x ^ ((c4 + 0) & 28))];
            u.y = tile[h][(c4 + 1) * 72 + (x ^ ((c4 + 1) & 28))];
            u.z = tile[h][(c4 + 2) * 72 + (x ^ ((c4 + 2) & 28))];
            u.w = tile[h][(c4 + 3) * 72 + (x ^ ((c4 + 3) & 28))];
            *(ushort4*)&dst[(size_t)x * CC + c4] = u;
        }
    }
}

// ---------------------------------------------------------------------------
// Fused line pipeline v4. 2 lines/block, 256 thr, 5 barriers.
// MFMA 16x16x32 bf16 mapping: A[m=lane&15][k=quad*8+j], C/D col=lane&15,
// row=quad*4+reg.
// ---------------------------------------------------------------------------
__global__ __launch_bounds__(256, 8)
void line_mfma(const unsigned short* __restrict__ fmT,   // (B,H,W,C) bf16
               const float* __restrict__ lines,
               const float* __restrict__ bn1_g, const float* __restrict__ bn1_b,
               const unsigned short* __restrict__ W1b, const float* __restrict__ b1,
               const float* __restrict__ bn2_g, const float* __restrict__ bn2_b,
               const unsigned short* __restrict__ W2b, const float* __restrict__ b2,
               const float* __restrict__ bn3_g, const float* __restrict__ bn3_b,
               const unsigned short* __restrict__ W3b, const float* __restrict__ b3,
               const float* __restrict__ fcwP,  const float* __restrict__ fcb,
               float* __restrict__ out) {
    __shared__ int   s_oA[64], s_oB[64], s_oC[64], s_oD[64];   // element offsets
    __shared__ float s_wA[64], s_wB[64], s_wC[64], s_wD[64];
    __shared__ float s_xs[16 * 132];             // residual, fp32, [m][c] pad 4
    __shared__ unsigned short s_ybn[16 * 136];   // relu(bn1), bf16, [m][c]
    __shared__ unsigned short s_z1[2 * 10 * 72]; // conv1 out, halo rows 0/9 zero
    __shared__ unsigned short s_z2[16 * 72];     // conv2 out, [m][q]
    __shared__ float s_feat[2][8];
    __shared__ float s_red[4 * 8];

    const int bx  = blockIdx.x;
    const int L0  = bx * 2;
    const int b   = bx >> 10;
    const int tid = threadIdx.x;
    const int lane = tid & 63;
    const int wv   = tid >> 6;
    const int quad = lane >> 4;
    const int l16  = lane & 15;
    const float inv_s = 1.0f / sqrtf(1.0f + 1e-5f);

    // ---- P0: per-point offsets/weights, line features, halo zeroing ----
    if (tid < 64) {
        int line = tid >> 5, pt = tid & 31;
        const float* ln = lines + (size_t)(L0 + line) * 4;
        float lam = (float)pt * (1.0f / 31.0f);
        float om  = 1.0f - lam;
        float px = ln[0] * lam + ln[2] * om - 0.5f;
        float py = ln[1] * lam + ln[3] * om - 0.5f;
        float px0 = fminf(fmaxf(floorf(px), 0.0f), 127.0f);
        float py0 = fminf(fmaxf(floorf(py), 0.0f), 127.0f);
        float px1 = fminf(px0 + 1.0f, 127.0f);
        float py1 = fminf(py0 + 1.0f, 127.0f);
        int ix0 = (int)px0, ix1 = (int)px1, iy0 = (int)py0, iy1 = (int)py1;
        s_oA[tid] = (iy0 * WW + ix0) * CC;
        s_oB[tid] = (iy1 * WW + ix0) * CC;
        s_oC[tid] = (iy0 * WW + ix1) * CC;
        s_oD[tid] = (iy1 * WW + ix1) * CC;
        float ax = px1 - px, bxv = px - px0, ay = py1 - py, byv = py - py0;
        // exact reference pairing (its bilinear weights are x/y-swapped)
        s_wA[tid] = ax  * ay;
        s_wB[tid] = bxv * ay;
        s_wC[tid] = ax  * byv;
        s_wD[tid] = bxv * byv;
    }
    if (tid >= 64 && tid < 66) {
        int line = tid - 64;
        const float* ln = lines + (size_t)(L0 + line) * 4;
        float ux = ln[0], uy = ln[1], vx = ln[2], vy = ln[3];
        float dx = ux - vx, dy = uy - vy;
        float d = fmaxf(sqrtf(dx * dx + dy * dy), 1e-6f);
        s_feat[line][0] = ux * (1.0f / 128.0f);
        s_feat[line][1] = uy * (1.0f / 128.0f);
        s_feat[line][2] = vx * (1.0f / 128.0f);
        s_feat[line][3] = vy * (1.0f / 128.0f);
        s_feat[line][4] = d;
    }
    if (tid < 128) {
        int line = tid >> 6, q = tid & 63;
        s_z1[line * 720 + 0 * 72 + q] = 0;
        s_z1[line * 720 + 9 * 72 + q] = 0;
    }
    __syncthreads();

    // ---- P1: bf16 gather + bilinear + maxpool(4) -> s_xs (fp32)
    //          + fused bn1+relu+cvt -> s_ybn ----
    {
        int tl = tid >> 4;               // m = line*8 + k, 0..15
        int line = tl >> 3, k = tl & 7;
        int c8 = (tid & 15) * 8;
        const unsigned short* base = fmT + (size_t)b * (HH * WW * CC) + c8;
        float acc[8];
        #pragma unroll
        for (int i = 0; i < 8; ++i) acc[i] = -INFINITY;
        #pragma unroll
        for (int j = 0; j < 4; ++j) {
            int pt = line * 32 + k * 4 + j;
            bf16x8 rA = *(const bf16x8*)(base + s_oA[pt]);
            bf16x8 rB = *(const bf16x8*)(base + s_oB[pt]);
            bf16x8 rC = *(const bf16x8*)(base + s_oC[pt]);
            bf16x8 rD = *(const bf16x8*)(base + s_oD[pt]);
            float wA = s_wA[pt], wB = s_wB[pt], wC = s_wC[pt], wD = s_wD[pt];
            #pragma unroll
            for (int i = 0; i < 8; ++i) {
                float v = wA * bf2f((unsigned short)rA[i])
                        + wB * bf2f((unsigned short)rB[i])
                        + wC * bf2f((unsigned short)rC[i])
                        + wD * bf2f((unsigned short)rD[i]);
                acc[i] = fmaxf(acc[i], v);
            }
        }
        float* xr = &s_xs[tl * 132 + c8];
        f32x4 lo = {acc[0], acc[1], acc[2], acc[3]};
        f32x4 hi = {acc[4], acc[5], acc[6], acc[7]};
        *(f32x4*)&xr[0] = lo;
        *(f32x4*)&xr[4] = hi;
        // fused bn1 + relu + cvt
        bf16x8 pack;
        #pragma unroll
        for (int i = 0; i < 8; ++i) {
            float v = fmaxf(acc[i] * (bn1_g[c8 + i] * inv_s) + bn1_b[c8 + i], 0.0f);
            pack[i] = (short)f2bf(v);
        }
        *(bf16x8*)&s_ybn[tl * 136 + c8] = pack;
    }
    __syncthreads();

    // ---- P2: conv1 (M=16,K=128,N=64) + bn2 + relu -> s_z1 ----
    {
        int n0 = wv * 16;
        f32x4 acc = {0.f, 0.f, 0.f, 0.f};
        #pragma unroll
        for (int kc = 0; kc < 4; ++kc) {
            bf16x8 a = *(const bf16x8*)&s_ybn[l16 * 136 + kc * 32 + quad * 8];
            bf16x8 bf = *(const bf16x8*)(W1b + (n0 + l16) * 128 + kc * 32 + quad * 8);
            acc = __builtin_amdgcn_mfma_f32_16x16x32_bf16(a, bf, acc, 0, 0, 0);
        }
        int p = n0 + l16;
        float s2 = bn2_g[p] * inv_s, bb2 = bn2_b[p], cb = b1[p];
        int line = quad >> 1;
        int kbase = (quad & 1) * 4;
        #pragma unroll
        for (int r = 0; r < 4; ++r) {
            float v = fmaxf((acc[r] + cb) * s2 + bb2, 0.0f);
            s_z1[line * 720 + (kbase + r + 1) * 72 + p] = f2bf(v);
        }
    }
    __syncthreads();

    // ---- P3: conv2 (3 shifted GEMMs, M=16,K=64,N=64) + bn3 + relu -> s_z2 ----
    {
        int n0 = wv * 16;
        f32x4 acc = {0.f, 0.f, 0.f, 0.f};
        int line = l16 >> 3, k = l16 & 7;
        #pragma unroll
        for (int t = 0; t < 3; ++t) {
            const unsigned short* arow = &s_z1[line * 720 + (k + t) * 72];
            #pragma unroll
            for (int kc = 0; kc < 2; ++kc) {
                bf16x8 a = *(const bf16x8*)&arow[kc * 32 + quad * 8];
                bf16x8 bf = *(const bf16x8*)(W2b + t * 4096 + (n0 + l16) * 64 + kc * 32 + quad * 8);
                acc = __builtin_amdgcn_mfma_f32_16x16x32_bf16(a, bf, acc, 0, 0, 0);
            }
        }
        int p = n0 + l16;
        float s3 = bn3_g[p] * inv_s, bb3 = bn3_b[p], cb = b2[p];
        #pragma unroll
        for (int r = 0; r < 4; ++r) {
            float v = fmaxf((acc[r] + cb) * s3 + bb3, 0.0f);
            s_z2[(quad * 4 + r) * 72 + p] = f2bf(v);
        }
    }
    __syncthreads();

    // ---- P4: conv3 (M=16,K=64,N=128) + residual + relu + fc2 partials ----
    float p0 = 0.f, p1 = 0.f, p2 = 0.f, p3 = 0.f;
    {
        int kbase = (quad & 1) * 4;
        bf16x8 a0 = *(const bf16x8*)&s_z2[l16 * 72 + 0 * 32 + quad * 8];
        bf16x8 a1 = *(const bf16x8*)&s_z2[l16 * 72 + 1 * 32 + quad * 8];
        #pragma unroll
        for (int sub = 0; sub < 2; ++sub) {
            int n0 = wv * 32 + sub * 16;
            f32x4 acc = {0.f, 0.f, 0.f, 0.f};
            bf16x8 bf0 = *(const bf16x8*)(W3b + (n0 + l16) * 64 + 0 * 32 + quad * 8);
            bf16x8 bf1 = *(const bf16x8*)(W3b + (n0 + l16) * 64 + 1 * 32 + quad * 8);
            acc = __builtin_amdgcn_mfma_f32_16x16x32_bf16(a0, bf0, acc, 0, 0, 0);
            acc = __builtin_amdgcn_mfma_f32_16x16x32_bf16(a1, bf1, acc, 0, 0, 0);
            int c = n0 + l16;
            float cb = b3[c];
            int idx = c * 8 + kbase;
            float4 w0 = *(const float4*)(fcwP + 0 * FCKP + idx);
            float4 w1v = *(const float4*)(fcwP + 1 * FCKP + idx);
            float4 w2v = *(const float4*)(fcwP + 2 * FCKP + idx);
            float4 w3v = *(const float4*)(fcwP + 3 * FCKP + idx);
            const float* w0a = (const float*)&w0;
            const float* w1a = (const float*)&w1v;
            const float* w2a = (const float*)&w2v;
            const float* w3a = (const float*)&w3v;
            #pragma unroll
            for (int r = 0; r < 4; ++r) {
                int m = quad * 4 + r;
                float v = fmaxf(s_xs[m * 132 + c] + acc[r] + cb, 0.0f);
                p0 = fmaf(v, w0a[r], p0);
                p1 = fmaf(v, w1a[r], p1);
                p2 = fmaf(v, w2a[r], p2);
                p3 = fmaf(v, w3a[r], p3);
            }
        }
    }
    #pragma unroll
    for (int off = 16; off >= 1; off >>= 1) {
        p0 += __shfl_down(p0, off);
        p1 += __shfl_down(p1, off);
        p2 += __shfl_down(p2, off);
        p3 += __shfl_down(p3, off);
    }
    if ((lane & 31) == 0) {
        int line = lane >> 5;
        s_red[wv * 8 + line * 4 + 0] = p0;
        s_red[wv * 8 + line * 4 + 1] = p1;
        s_red[wv * 8 + line * 4 + 2] = p2;
        s_red[wv * 8 + line * 4 + 3] = p3;
    }
    __syncthreads();

    // ---- P5: finish logits + softmax ----
    if (tid < 2) {
        int line = tid;
        float lg[4];
        #pragma unroll
        for (int o = 0; o < 4; ++o) {
            lg[o] = fcb[o] + s_red[0 + line * 4 + o] + s_red[8 + line * 4 + o]
                  + s_red[16 + line * 4 + o] + s_red[24 + line * 4 + o];
        }
        #pragma unroll
        for (int j = 0; j < FDIM; ++j) {
            float fv = fmaxf(s_feat[line][j], 0.0f);
            #pragma unroll
            for (int o = 0; o < 4; ++o)
                lg[o] = fmaf(fv, fcwP[o * FCKP + 1024 + j], lg[o]);
        }
        float m = fmaxf(fmaxf(lg[0], lg[1]), fmaxf(lg[2], lg[3]));
        float e0 = expf(lg[0] - m), e1 = expf(lg[1] - m);
        float e2 = expf(lg[2] - m), e3 = expf(lg[3] - m);
        float inv = 1.0f / (e0 + e1 + e2 + e3);
        float* lo = out + (size_t)(L0 + line) * 4;
        lo[0] = lg[0]; lo[1] = lg[1]; lo[2] = lg[2]; lo[3] = lg[3];
        float* pr = out + (size_t)BB * NLL * 4 + (size_t)(L0 + line) * 4;
        pr[0] = e0 * inv; pr[1] = e1 * inv; pr[2] = e2 * inv; pr[3] = e3 * inv;
    }
}

// ---------------------------------------------------------------------------
// Fallbacks (small-ws paths): round-1 proven VALU kernel + fp32 transpose.
// ---------------------------------------------------------------------------
__global__ __launch_bounds__(256)
void transpose_fm2(const float* __restrict__ fm, float* __restrict__ fmT) {
    __shared__ float tile[32 * 132];
    const int c0 = blockIdx.x * 32;
    const int by = blockIdx.y;
    const int b = by >> 7, y = by & 127;
    const int t = threadIdx.x;
    const float* src = fm + ((size_t)b * CC) * (HH * WW) + (size_t)y * WW;
    const int x4 = (t & 31) * 4;
    #pragma unroll
    for (int i = 0; i < 4; ++i) {
        int r = (t >> 5) + 8 * i;
        *(float4*)&tile[r * 132 + x4] =
            *(const float4*)&src[(size_t)(c0 + r) * (HH * WW) + x4];
    }
    __syncthreads();
    float* dst = fmT + (size_t)by * WW * CC + c0 + (t & 31);
    const int cr = (t & 31) * 132;
    #pragma unroll
    for (int i = 0; i < 16; ++i) {
        int x = (t >> 5) + 8 * i;
        dst[(size_t)x * CC] = tile[cr + x];
    }
}

template<bool TRANS>
__global__ __launch_bounds__(256)
void line_kernel_v1(const float* __restrict__ fm,
                    const float* __restrict__ lines,
                    const float* __restrict__ bn1_g, const float* __restrict__ bn1_b,
                    const float* __restrict__ w1,    const float* __restrict__ b1,
                    const float* __restrict__ bn2_g, const float* __restrict__ bn2_b,
                    const float* __restrict__ w2,    const float* __restrict__ b2,
                    const float* __restrict__ bn3_g, const float* __restrict__ bn3_b,
                    const float* __restrict__ w3,    const float* __restrict__ b3,
                    const float* __restrict__ fcw,   const float* __restrict__ fcb,
                    float* __restrict__ out) {
    __shared__ int   s_ix0[32], s_ix1[32], s_iy0[32], s_iy1[32];
    __shared__ float s_wA[32], s_wB[32], s_wC[32], s_wD[32];
    __shared__ float xs [8][132];
    __shared__ float ybn[8][132];
    __shared__ float z1 [64][12];
    __shared__ float z2 [64][8];
    __shared__ float s_feat[8];
    __shared__ float s_red[16];

    const int L   = blockIdx.x;
    const int b   = L / NLL;
    const int tid = threadIdx.x;
    const float inv_s = 1.0f / sqrtf(1.0f + 1e-5f);
    const float* ln = lines + (size_t)L * 4;

    if (tid < 32) {
        float lam = (float)tid * (1.0f / 31.0f);
        float om  = 1.0f - lam;
        float px = ln[0] * lam + ln[2] * om - 0.5f;
        float py = ln[1] * lam + ln[3] * om - 0.5f;
        float px0 = fminf(fmaxf(floorf(px), 0.0f), 127.0f);
        float py0 = fminf(fmaxf(floorf(py), 0.0f), 127.0f);
        float px1 = fminf(px0 + 1.0f, 127.0f);
        float py1 = fminf(py0 + 1.0f, 127.0f);
        s_ix0[tid] = (int)px0; s_ix1[tid] = (int)px1;
        s_iy0[tid] = (int)py0; s_iy1[tid] = (int)py1;
        float ax = px1 - px, bxv = px - px0, ay = py1 - py, byv = py - py0;
        s_wA[tid] = ax  * ay;  s_wB[tid] = bxv * ay;
        s_wC[tid] = ax  * byv; s_wD[tid] = bxv * byv;
    }
    if (tid == 0) {
        float ux = ln[0], uy = ln[1], vx = ln[2], vy = ln[3];
        float dx = ux - vx, dy = uy - vy;
        float d = fmaxf(sqrtf(dx * dx + dy * dy), 1e-6f);
        s_feat[0] = ux / 128.0f; s_feat[1] = uy / 128.0f;
        s_feat[2] = vx / 128.0f; s_feat[3] = vy / 128.0f;
        s_feat[4] = d;
    }
    __syncthreads();
    {
        int cq = tid & 31, k = tid >> 5, c0 = cq * 4;
        float4 acc;
        acc.x = -INFINITY; acc.y = -INFINITY; acc.z = -INFINITY; acc.w = -INFINITY;
        #pragma unroll
        for (int j = 0; j < 4; ++j) {
            int pt = k * 4 + j;
            int ix0 = s_ix0[pt], ix1 = s_ix1[pt];
            int iy0 = s_iy0[pt], iy1 = s_iy1[pt];
            float wA = s_wA[pt], wB = s_wB[pt], wC = s_wC[pt], wD = s_wD[pt];
            float4 vA, vB, vC, vD;
            if (TRANS) {
                const float* base = fm + (size_t)b * HH * WW * CC;
                vA = *(const float4*)(base + ((size_t)(iy0 * WW + ix0)) * CC + c0);
                vB = *(const float4*)(base + ((size_t)(iy1 * WW + ix0)) * CC + c0);
                vC = *(const float4*)(base + ((size_t)(iy0 * WW + ix1)) * CC + c0);
                vD = *(const float4*)(base + ((size_t)(iy1 * WW + ix1)) * CC + c0);
            } else {
                const float* base = fm + ((size_t)b * CC + c0) * HH * WW;
                int oA = iy0 * WW + ix0, oB = iy1 * WW + ix0;
                int oC = iy0 * WW + ix1, oD = iy1 * WW + ix1;
                vA.x = base[oA];           vB.x = base[oB];
                vC.x = base[oC];           vD.x = base[oD];
                vA.y = base[HH*WW + oA];   vB.y = base[HH*WW + oB];
                vC.y = base[HH*WW + oC];   vD.y = base[HH*WW + oD];
                vA.z = base[2*HH*WW + oA]; vB.z = base[2*HH*WW + oB];
                vC.z = base[2*HH*WW + oC]; vD.z = base[2*HH*WW + oD];
                vA.w = base[3*HH*WW + oA]; vB.w = base[3*HH*WW + oB];
                vC.w = base[3*HH*WW + oC]; vD.w = base[3*HH*WW + oD];
            }
            float4 v;
            v.x = wA * vA.x + wB * vB.x + wC * vC.x + wD * vD.x;
            v.y = wA * vA.y + wB * vB.y + wC * vC.y + wD * vD.y;
            v.z = wA * vA.z + wB * vB.z + wC * vC.z + wD * vD.z;
            v.w = wA * vA.w + wB * vB.w + wC * vC.w + wD * vD.w;
            acc.x = fmaxf(acc.x, v.x); acc.y = fmaxf(acc.y, v.y);
            acc.z = fmaxf(acc.z, v.z); acc.w = fmaxf(acc.w, v.w);
        }
        *(float4*)(&xs[k][c0]) = acc;
    }
    __syncthreads();
    for (int e = tid; e < 1024; e += 256) {
        int k = e >> 7, c = e & 127;
        ybn[k][c] = fmaxf(xs[k][c] * (bn1_g[c] * inv_s) + bn1_b[c], 0.0f);
    }
    __syncthreads();
    if (tid < 64) { z1[tid][0] = 0.0f; z1[tid][9] = 0.0f; }
    {
        int p = tid >> 2, kq = tid & 3;
        const float* wrow = w1 + p * 128;
        float a0a = 0.f, a0b = 0.f, a1a = 0.f, a1b = 0.f;
        #pragma unroll 8
        for (int c = 0; c < 128; c += 4) {
            float4 w  = *(const float4*)(wrow + c);
            float4 ya = *(const float4*)(&ybn[kq][c]);
            float4 yb = *(const float4*)(&ybn[kq + 4][c]);
            a0a = fmaf(w.x, ya.x, a0a); a0b = fmaf(w.y, ya.y, a0b);
            a0a = fmaf(w.z, ya.z, a0a); a0b = fmaf(w.w, ya.w, a0b);
            a1a = fmaf(w.x, yb.x, a1a); a1b = fmaf(w.y, yb.y, a1b);
            a1a = fmaf(w.z, yb.z, a1a); a1b = fmaf(w.w, yb.w, a1b);
        }
        float s2 = bn2_g[p] * inv_s, bb = bn2_b[p], cb = b1[p];
        z1[p][1 + kq]     = fmaxf((a0a + a0b + cb) * s2 + bb, 0.0f);
        z1[p][1 + kq + 4] = fmaxf((a1a + a1b + cb) * s2 + bb, 0.0f);
    }
    __syncthreads();
    {
        int p = tid >> 2, kq = tid & 3;
        const float* wrow = w2 + p * 192;
        float acc0 = 0.f, acc1 = 0.f;
        #pragma unroll 4
        for (int q = 0; q < 64; ++q) {
            float w0 = wrow[q * 3 + 0], w1v = wrow[q * 3 + 1], w2v = wrow[q * 3 + 2];
            const float* zr = &z1[q][0];
            acc0 = fmaf(w0, zr[kq], acc0);
            acc0 = fmaf(w1v, zr[kq + 1], acc0);
            acc0 = fmaf(w2v, zr[kq + 2], acc0);
            acc1 = fmaf(w0, zr[kq + 4], acc1);
            acc1 = fmaf(w1v, zr[kq + 5], acc1);
            acc1 = fmaf(w2v, zr[kq + 6], acc1);
        }
        float s3 = bn3_g[p] * inv_s, bb = bn3_b[p], cb = b2[p];
        z2[p][kq]     = fmaxf((acc0 + cb) * s3 + bb, 0.0f);
        z2[p][kq + 4] = fmaxf((acc1 + cb) * s3 + bb, 0.0f);
    }
    __syncthreads();
    float part0 = 0.f, part1 = 0.f, part2 = 0.f, part3 = 0.f;
    {
        int c = tid >> 1, kq = tid & 1;
        const float* wrow = w3 + c * 64;
        float acc[4] = {0.f, 0.f, 0.f, 0.f};
        #pragma unroll 8
        for (int q = 0; q < 64; ++q) {
            float w = wrow[q];
            acc[0] = fmaf(w, z2[q][kq], acc[0]);
            acc[1] = fmaf(w, z2[q][kq + 2], acc[1]);
            acc[2] = fmaf(w, z2[q][kq + 4], acc[2]);
            acc[3] = fmaf(w, z2[q][kq + 6], acc[3]);
        }
        float cb = b3[c];
        #pragma unroll
        for (int i = 0; i < 4; ++i) {
            int k = kq + 2 * i;
            float v = fmaxf(xs[k][c] + acc[i] + cb, 0.0f);
            int idx = c * 8 + k;
            part0 = fmaf(v, fcw[0 * FCK + idx], part0);
            part1 = fmaf(v, fcw[1 * FCK + idx], part1);
            part2 = fmaf(v, fcw[2 * FCK + idx], part2);
            part3 = fmaf(v, fcw[3 * FCK + idx], part3);
        }
    }
    #pragma unroll
    for (int off = 32; off > 0; off >>= 1) {
        part0 += __shfl_down(part0, off);
        part1 += __shfl_down(part1, off);
        part2 += __shfl_down(part2, off);
        part3 += __shfl_down(part3, off);
    }
    if ((tid & 63) == 0) {
        int w = tid >> 6;
        s_red[w * 4 + 0] = part0; s_red[w * 4 + 1] = part1;
        s_red[w * 4 + 2] = part2; s_red[w * 4 + 3] = part3;
    }
    __syncthreads();
    if (tid == 0) {
        float lg[4];
        #pragma unroll
        for (int o = 0; o < 4; ++o)
            lg[o] = fcb[o] + s_red[o] + s_red[4 + o] + s_red[8 + o] + s_red[12 + o];
        #pragma unroll
        for (int j = 0; j < FDIM; ++j) {
            float fv = fmaxf(s_feat[j], 0.0f);
            #pragma unroll
            for (int o = 0; o < 4; ++o)
                lg[o] = fmaf(fv, fcw[o * FCK + 1024 + j], lg[o]);
        }
        float m = fmaxf(fmaxf(lg[0], lg[1]), fmaxf(lg[2], lg[3]));
        float e0 = expf(lg[0] - m), e1 = expf(lg[1] - m);
        float e2 = expf(lg[2] - m), e3 = expf(lg[3] - m);
        float inv = 1.0f / (e0 + e1 + e2 + e3);
        float* lo = out + (size_t)L * 4;
        lo[0] = lg[0]; lo[1] = lg[1]; lo[2] = lg[2]; lo[3] = lg[3];
        float* pr = out + (size_t)BB * NLL * 4 + (size_t)L * 4;
        pr[0] = e0 * inv; pr[1] = e1 * inv; pr[2] = e2 * inv; pr[3] = e3 * inv;
    }
}

extern "C" void kernel_launch(void* const* d_in, const int* in_sizes, int n_in,
                              void* d_out, int out_size, void* d_ws, size_t ws_size,
                              hipStream_t stream) {
    const float* fm     = (const float*)d_in[0];
    const float* lines  = (const float*)d_in[1];
    const float* bn1_g  = (const float*)d_in[2];
    const float* bn1_b  = (const float*)d_in[3];
    const float* w1     = (const float*)d_in[4];
    const float* b1     = (const float*)d_in[5];
    const float* bn2_g  = (const float*)d_in[6];
    const float* bn2_b  = (const float*)d_in[7];
    const float* w2     = (const float*)d_in[8];
    const float* b2     = (const float*)d_in[9];
    const float* bn3_g  = (const float*)d_in[10];
    const float* bn3_b  = (const float*)d_in[11];
    const float* w3     = (const float*)d_in[12];
    const float* b3     = (const float*)d_in[13];
    const float* fcw    = (const float*)d_in[14];
    const float* fcb    = (const float*)d_in[15];
    float* out = (float*)d_out;

    const size_t fmTb_bytes = (size_t)BB * HH * WW * CC * sizeof(unsigned short); // 8 MiB
    const size_t fmTf_bytes = (size_t)BB * HH * WW * CC * sizeof(float);          // 32 MiB
    const size_t wb_bytes   = 57344;                    // W1b+W2b+W3b (bf16)
    const size_t fcwP_bytes = 4 * FCKP * sizeof(float); // 16512

    if (ws_size >= fmTb_bytes + wb_bytes + fcwP_bytes) {
        unsigned short* fmT = (unsigned short*)d_ws;
        unsigned short* W1b = (unsigned short*)((char*)d_ws + fmTb_bytes);
        unsigned short* W2b = W1b + 8192;
        unsigned short* W3b = W2b + 12288;
        float* fcwP = (float*)((char*)d_ws + fmTb_bytes + wb_bytes);
        transpose_prep<<<512 + 16, 256, 0, stream>>>(
            fm, w1, w2, w3, fcw, fmT, W1b, W2b, W3b, fcwP);
        line_mfma<<<BB * NLL / 2, 256, 0, stream>>>(
            fmT, lines, bn1_g, bn1_b, W1b, b1, bn2_g, bn2_b, W2b, b2,
            bn3_g, bn3_b, W3b, b3, fcwP, fcb, out);
    } else if (ws_size >= fmTf_bytes) {
        float* fmT = (float*)d_ws;
        dim3 tg(CC / 32, BB * HH);
        transpose_fm2<<<tg, 256, 0, stream>>>(fm, fmT);
        line_kernel_v1<true><<<BB * NLL, 256, 0, stream>>>(
            fmT, lines, bn1_g, bn1_b, w1, b1, bn2_g, bn2_b, w2, b2,
            bn3_g, bn3_b, w3, b3, fcw, fcb, out);
    } else {
        line_kernel_v1<false><<<BB * NLL, 256, 0, stream>>>(
            fm, lines, bn1_g, bn1_b, w1, b1, bn2_g, bn2_b, w2, b2,
            bn3_g, bn3_b, w3, b3, fcw, fcb, out);
    }
}